// Round 1
// baseline (1317.419 us; speedup 1.0000x reference)
//
#include <hip/hip_runtime.h>
#include <math.h>

// Problem constants
constexpr int cB = 48, cN = 512, cIN = 400;
constexpr int cENC = 256, cHID = 128, cOUT = 128, cNREL = 53;
constexpr int cKNN = 10;
constexpr float cVSN = 1e-12f;
constexpr float cEPS = 0.3f;
constexpr float cSKIP = 0.8f;

__device__ inline unsigned long long shfl_xor_u64(unsigned long long v, int off) {
    int lo = __shfl_xor((int)(unsigned)(v & 0xffffffffull), off, 64);
    int hi = __shfl_xor((int)(unsigned)(v >> 32), off, 64);
    return ((unsigned long long)(unsigned)hi << 32) | (unsigned)lo;
}

// ---------------- K0: mask + per-perspective inverse norms ----------------
__global__ void k_prep(const float* __restrict__ X, const int* __restrict__ lens,
                       const float* __restrict__ glw,
                       float* __restrict__ mask, float* __restrict__ invn)
{
    int row = blockIdx.x * 4 + (threadIdx.x >> 6);
    int lane = threadIdx.x & 63;
    if (row >= cB * cN) return;
    int b = row >> 9, n = row & (cN - 1);
    float s0 = 0.f, s1 = 0.f, s2 = 0.f, s3 = 0.f;
    const float* x = X + (long long)row * cIN;
    for (int d = lane; d < cIN; d += 64) {
        float xv = x[d];
        float x2 = xv * xv;
        float w0 = glw[0 * cIN + d], w1 = glw[1 * cIN + d];
        float w2 = glw[2 * cIN + d], w3 = glw[3 * cIN + d];
        s0 += x2 * w0 * w0;
        s1 += x2 * w1 * w1;
        s2 += x2 * w2 * w2;
        s3 += x2 * w3 * w3;
    }
    #pragma unroll
    for (int off = 32; off; off >>= 1) {
        s0 += __shfl_xor(s0, off, 64);
        s1 += __shfl_xor(s1, off, 64);
        s2 += __shfl_xor(s2, off, 64);
        s3 += __shfl_xor(s3, off, 64);
    }
    if (lane == 0) {
        mask[row] = (n < lens[b]) ? 1.0f : 0.0f;
        invn[0 * (cB * cN) + row] = 1.0f / fmaxf(sqrtf(s0), cVSN);
        invn[1 * (cB * cN) + row] = 1.0f / fmaxf(sqrtf(s1), cVSN);
        invn[2 * (cB * cN) + row] = 1.0f / fmaxf(sqrtf(s2), cVSN);
        invn[3 * (cB * cN) + row] = 1.0f / fmaxf(sqrtf(s3), cVSN);
    }
}

// ---------------- K1: fused similarity (plain dot + 4 weighted dots) ----------------
__global__ __launch_bounds__(256) void k_sim(
    const float* __restrict__ X, const float* __restrict__ glw,
    const float* __restrict__ mask, const float* __restrict__ invn,
    float* __restrict__ G0, float* __restrict__ RA)
{
    const int b = blockIdx.z;
    const int n0 = blockIdx.y * 64, m0 = blockIdx.x * 64;
    __shared__ float Xa[16][68];   // [k][row]
    __shared__ float Xb[16][68];
    __shared__ float W2[4][16];
    const float* Xbase = X + (long long)b * cN * cIN;
    const int t = threadIdx.x;
    const int tx = t & 15, ty = t >> 4;

    float acc[5][4][4];
    #pragma unroll
    for (int w = 0; w < 5; ++w)
        #pragma unroll
        for (int i = 0; i < 4; ++i)
            #pragma unroll
            for (int j = 0; j < 4; ++j) acc[w][i][j] = 0.f;

    for (int k0 = 0; k0 < cIN; k0 += 16) {
        #pragma unroll
        for (int i = 0; i < 4; ++i) {
            int e = t + i * 256;
            int r = e >> 4, c = e & 15;
            Xa[c][r] = Xbase[(long long)(n0 + r) * cIN + k0 + c];
            Xb[c][r] = Xbase[(long long)(m0 + r) * cIN + k0 + c];
        }
        if (t < 64) {
            int p = t >> 4, c = t & 15;
            float w = glw[p * cIN + k0 + c];
            W2[p][c] = w * w;
        }
        __syncthreads();
        #pragma unroll
        for (int kk = 0; kk < 16; ++kk) {
            float a[4], bb[4], w2k[4];
            #pragma unroll
            for (int i = 0; i < 4; ++i) a[i] = Xa[kk][ty * 4 + i];
            #pragma unroll
            for (int j = 0; j < 4; ++j) bb[j] = Xb[kk][tx * 4 + j];
            #pragma unroll
            for (int p = 0; p < 4; ++p) w2k[p] = W2[p][kk];
            #pragma unroll
            for (int i = 0; i < 4; ++i)
                #pragma unroll
                for (int j = 0; j < 4; ++j) {
                    float tt = a[i] * bb[j];
                    acc[0][i][j] += tt;
                    acc[1][i][j] += tt * w2k[0];
                    acc[2][i][j] += tt * w2k[1];
                    acc[3][i][j] += tt * w2k[2];
                    acc[4][i][j] += tt * w2k[3];
                }
        }
        __syncthreads();
    }

    long long rowBase = (long long)b * cN;
    float mn[4], mm[4];
    float in_n[4][4], in_m[4][4];   // [p][i]
    #pragma unroll
    for (int i = 0; i < 4; ++i) {
        mn[i] = mask[rowBase + n0 + ty * 4 + i];
        mm[i] = mask[rowBase + m0 + tx * 4 + i];
        #pragma unroll
        for (int p = 0; p < 4; ++p) {
            in_n[p][i] = invn[p * (cB * cN) + rowBase + n0 + ty * 4 + i];
            in_m[p][i] = invn[p * (cB * cN) + rowBase + m0 + tx * 4 + i];
        }
    }
    #pragma unroll
    for (int i = 0; i < 4; ++i) {
        int n = n0 + ty * 4 + i;
        long long base = ((long long)b * cN + n) * cN + m0 + tx * 4;
        float gv[4], rv[4];
        #pragma unroll
        for (int j = 0; j < 4; ++j) {
            float m2 = mn[i] * mm[j];
            gv[j] = acc[0][i][j] * m2;
            float s = 0.25f * (acc[1][i][j] * in_n[0][i] * in_m[0][j]
                             + acc[2][i][j] * in_n[1][i] * in_m[1][j]
                             + acc[3][i][j] * in_n[2][i] * in_m[2][j]
                             + acc[4][i][j] * in_n[3][i] * in_m[3][j]) * m2;
            rv[j] = (s > cEPS) ? s : 0.f;
        }
        *(float4*)(G0 + base) = make_float4(gv[0], gv[1], gv[2], gv[3]);
        *(float4*)(RA + base) = make_float4(rv[0], rv[1], rv[2], rv[3]);
    }
}

// ---------------- K1b: row sums of sparsified RA ----------------
__global__ void k_rowsum(const float* __restrict__ RA, float* __restrict__ rowsum)
{
    int row = blockIdx.x * 4 + (threadIdx.x >> 6);
    int lane = threadIdx.x & 63;
    const float* r = RA + (long long)row * cN;
    float s = 0.f;
    #pragma unroll
    for (int k = 0; k < 8; ++k) s += r[lane + 64 * k];
    #pragma unroll
    for (int off = 32; off; off >>= 1) s += __shfl_xor(s, off, 64);
    if (lane == 0) rowsum[row] = fmaxf(s, cVSN);
}

// ---------------- K2: per-row top-10 (value desc, index asc) ----------------
__global__ void k_topk(const float* __restrict__ G0, const float* __restrict__ mask,
                       int* __restrict__ kidx, float* __restrict__ rinv)
{
    int row = blockIdx.x * 4 + (threadIdx.x >> 6);
    int lane = threadIdx.x & 63;
    int b = row >> 9, n = row & (cN - 1);
    const float* g = G0 + (long long)row * cN;
    unsigned long long key[8];
    #pragma unroll
    for (int k = 0; k < 8; ++k) {
        int col = lane + 64 * k;
        float v = g[col];
        unsigned u = __float_as_uint(v);
        u ^= (unsigned)(((int)u >> 31)) | 0x80000000u;
        key[k] = ((unsigned long long)u << 32) | (unsigned)(cN - 1 - col);
    }
    float cnt = 0.f;
    long long mbase = (long long)b * cN;
    for (int r = 0; r < cKNN; ++r) {
        unsigned long long best = 0ull;
        #pragma unroll
        for (int k = 0; k < 8; ++k) best = (key[k] > best) ? key[k] : best;
        #pragma unroll
        for (int off = 32; off; off >>= 1) {
            unsigned long long o = shfl_xor_u64(best, off);
            if (o > best) best = o;
        }
        int col = (cN - 1) - (int)(best & 0xffffffffull);
        #pragma unroll
        for (int k = 0; k < 8; ++k) if (key[k] == best) key[k] = 0ull;
        if (lane == 0) {
            kidx[row * cKNN + r] = col;
            cnt += mask[mbase + col];
        }
    }
    if (lane == 0) {
        float mk = mask[mbase + n];
        rinv[row] = (mk > 0.f) ? rsqrtf(fmaxf(cnt, cVSN)) : 0.f;
    }
}

// ---------------- K3: final adjacency assembly ----------------
__global__ void k_adj(const float* __restrict__ RA, const float* __restrict__ rowsum,
                      const float* __restrict__ rinv, const int* __restrict__ kidx,
                      float* __restrict__ ADJ)
{
    int row = blockIdx.x;
    int t = threadIdx.x;  // 256
    __shared__ int sidx[cKNN];
    __shared__ float srv[cKNN];
    long long bbase = (long long)(row & ~(cN - 1));
    if (t < cKNN) {
        int c = kidx[row * cKNN + t];
        sidx[t] = c;
        srv[t] = rinv[bbase + c];
    }
    __syncthreads();
    float rn = rinv[row];
    float inv_rs = 1.0f / rowsum[row];
    long long base = (long long)row * cN;
    #pragma unroll
    for (int mi = 0; mi < 2; ++mi) {
        int m = t + mi * 256;
        float v = (1.0f - cSKIP) * RA[base + m] * inv_rs;
        #pragma unroll
        for (int k = 0; k < cKNN; ++k)
            if (m == sidx[k]) v += cSKIP * rn * srv[k];
        ADJ[base + m] = v;
    }
}

// ---------------- Generic tiled fp32 GEMM: C = A@B (+bias)(relu), batched ----------------
template<bool RELU, bool BIAS>
__global__ __launch_bounds__(256) void k_gemm(
    const float* __restrict__ A, const float* __restrict__ Bm,
    const float* __restrict__ bias, float* __restrict__ C,
    int M, int Nc, int K,
    long long sA, long long sB, long long sC)
{
    const int bz = blockIdx.z;
    A += (long long)bz * sA;
    Bm += (long long)bz * sB;
    C += (long long)bz * sC;
    const int bm = blockIdx.y * 64, bn = blockIdx.x * 64;
    __shared__ float As[16][68];   // [k][row]
    __shared__ float Bs[16][68];   // [k][col]
    const int t = threadIdx.x, tx = t & 15, ty = t >> 4;
    float acc[4][4];
    #pragma unroll
    for (int i = 0; i < 4; ++i)
        #pragma unroll
        for (int j = 0; j < 4; ++j) acc[i][j] = 0.f;

    for (int k0 = 0; k0 < K; k0 += 16) {
        #pragma unroll
        for (int i = 0; i < 4; ++i) {
            int e = t + i * 256;
            { int r = e >> 4, c = e & 15;
              As[c][r] = A[(long long)(bm + r) * K + k0 + c]; }
            { int r = e >> 6, c = e & 63;
              Bs[r][c] = Bm[(long long)(k0 + r) * Nc + bn + c]; }
        }
        __syncthreads();
        #pragma unroll
        for (int kk = 0; kk < 16; ++kk) {
            float a[4], bb[4];
            #pragma unroll
            for (int i = 0; i < 4; ++i) a[i] = As[kk][ty * 4 + i];
            #pragma unroll
            for (int j = 0; j < 4; ++j) bb[j] = Bs[kk][tx * 4 + j];
            #pragma unroll
            for (int i = 0; i < 4; ++i)
                #pragma unroll
                for (int j = 0; j < 4; ++j)
                    acc[i][j] += a[i] * bb[j];
        }
        __syncthreads();
    }
    #pragma unroll
    for (int i = 0; i < 4; ++i) {
        long long r = bm + ty * 4 + i;
        float ov[4];
        #pragma unroll
        for (int j = 0; j < 4; ++j) {
            float v = acc[i][j];
            if (BIAS) v += bias[bn + tx * 4 + j];
            if (RELU) v = fmaxf(v, 0.f);
            ov[j] = v;
        }
        *(float4*)(C + r * Nc + bn + tx * 4) = make_float4(ov[0], ov[1], ov[2], ov[3]);
    }
}

// ---------------- K5: maxpool + mention merge + final linear ----------------
__global__ void k_final(const float* __restrict__ nv, const int* __restrict__ mentions,
                        const float* __restrict__ lw, const float* __restrict__ lb,
                        float* __restrict__ out)
{
    int b = blockIdx.x;
    int t = threadIdx.x;            // 512
    int d = t & 127, g = t >> 7;    // 4 row-groups
    __shared__ float smx[4][128], sa1[4][128], sa2[4][128];
    int s1 = mentions[b * 4 + 0], e1 = mentions[b * 4 + 1];
    int s2 = mentions[b * 4 + 2], e2 = mentions[b * 4 + 3];
    const float* p = nv + (long long)b * cN * cOUT;
    float mx = -INFINITY, a1 = 0.f, a2 = 0.f;
    for (int n = g * 128; n < (g + 1) * 128; ++n) {
        float v = p[n * cOUT + d];
        mx = fmaxf(mx, v);
        if (n >= s1 && n <= e1) a1 += v;
        if (n >= s2 && n <= e2) a2 += v;
    }
    smx[g][d] = mx; sa1[g][d] = a1; sa2[g][d] = a2;
    __syncthreads();
    if (t < 128) {
        float m2 = fmaxf(fmaxf(smx[0][t], smx[1][t]), fmaxf(smx[2][t], smx[3][t]));
        float b1s = sa1[0][t] + sa1[1][t] + sa1[2][t] + sa1[3][t];
        float b2s = sa2[0][t] + sa2[1][t] + sa2[2][t] + sa2[3][t];
        smx[0][t] = m2 + b1s / (float)(e1 - s1 + 1) + b2s / (float)(e2 - s2 + 1);
    }
    __syncthreads();
    if (t < cNREL) {
        float s = lb[t];
        for (int dd = 0; dd < cOUT; ++dd) s += smx[0][dd] * lw[dd * cNREL + t];
        out[b * cNREL + t] = s;
    }
}

extern "C" void kernel_launch(void* const* d_in, const int* in_sizes, int n_in,
                              void* d_out, int out_size, void* d_ws, size_t ws_size,
                              hipStream_t stream)
{
    const float* context = (const float*)d_in[0];
    const int*   lens    = (const int*)d_in[1];
    const int*   ments   = (const int*)d_in[2];
    const float* w_enc   = (const float*)d_in[3];
    const float* b_enc   = (const float*)d_in[4];
    const float* glw     = (const float*)d_in[5];
    const float* w1      = (const float*)d_in[6];
    const float* b1      = (const float*)d_in[7];
    const float* w2      = (const float*)d_in[8];
    const float* b2      = (const float*)d_in[9];
    const float* lw      = (const float*)d_in[10];
    const float* lb      = (const float*)d_in[11];
    float* out = (float*)d_out;

    float* ws = (float*)d_ws;
    float* ADJ  = ws;                               // 48*512*512, holds G0 then final adj
    float* RA   = ADJ + (size_t)cB * cN * cN;       // 48*512*512, holds RA then t1/h/t2
    float* enc  = RA + (size_t)cB * cN * cN;        // 48*512*256
    float* nv   = enc + (size_t)cB * cN * cENC;     // 48*512*128
    float* invn = nv + (size_t)cB * cN * cOUT;      // 4*48*512
    float* maskA = invn + 4 * (size_t)cB * cN;      // 48*512
    float* rinv  = maskA + (size_t)cB * cN;         // 48*512
    float* rowsum = rinv + (size_t)cB * cN;         // 48*512
    int*   kidx = (int*)(rowsum + (size_t)cB * cN); // 48*512*10
    float* t1 = RA;                                 // after k_adj, RA is dead
    float* h  = t1 + (size_t)cB * cN * cENC;
    float* t2 = h + (size_t)cB * cN * cHID;

    k_prep<<<cB * cN / 4, 256, 0, stream>>>(context, lens, glw, maskA, invn);
    k_sim<<<dim3(8, 8, cB), 256, 0, stream>>>(context, glw, maskA, invn, ADJ, RA);
    k_rowsum<<<cB * cN / 4, 256, 0, stream>>>(RA, rowsum);
    k_topk<<<cB * cN / 4, 256, 0, stream>>>(ADJ, maskA, kidx, rinv);
    k_adj<<<cB * cN, 256, 0, stream>>>(RA, rowsum, rinv, kidx, ADJ);

    // enc = context @ w_enc + b_enc
    k_gemm<false, true><<<dim3(cENC / 64, (cB * cN) / 64, 1), 256, 0, stream>>>(
        context, w_enc, b_enc, enc, cB * cN, cENC, cIN, 0, 0, 0);
    // t1 = adj @ enc  (batched)
    k_gemm<false, false><<<dim3(cENC / 64, cN / 64, cB), 256, 0, stream>>>(
        ADJ, enc, nullptr, t1, cN, cENC, cN,
        (long long)cN * cN, (long long)cN * cENC, (long long)cN * cENC);
    // h = relu(t1 @ w1 + b1)
    k_gemm<true, true><<<dim3(cHID / 64, (cB * cN) / 64, 1), 256, 0, stream>>>(
        t1, w1, b1, h, cB * cN, cHID, cENC, 0, 0, 0);
    // t2 = adj @ h  (batched)
    k_gemm<false, false><<<dim3(cHID / 64, cN / 64, cB), 256, 0, stream>>>(
        ADJ, h, nullptr, t2, cN, cHID, cN,
        (long long)cN * cN, (long long)cN * cHID, (long long)cN * cHID);
    // nv = t2 @ w2 + b2
    k_gemm<false, true><<<dim3(cOUT / 64, (cB * cN) / 64, 1), 256, 0, stream>>>(
        t2, w2, b2, nv, cB * cN, cOUT, cHID, 0, 0, 0);

    k_final<<<cB, 512, 0, stream>>>(nv, ments, lw, lb, out);
}

// Round 2
// 613.131 us; speedup vs baseline: 2.1487x; 2.1487x over previous
//
#include <hip/hip_runtime.h>
#include <math.h>

// Problem constants
constexpr int cB = 48, cN = 512, cIN = 400;
constexpr int cENC = 256, cHID = 128, cOUT = 128, cNREL = 53;
constexpr int cKNN = 10;
constexpr float cVSN = 1e-12f;
constexpr float cEPS = 0.3f;
constexpr float cSKIP = 0.8f;

constexpr int KP = 416;                       // cIN padded to multiple of 32
constexpr size_t ARRSZ = (size_t)cB * cN * KP; // elems per f16 array (10,223,616)

typedef _Float16 f16;
typedef _Float16 f16x8 __attribute__((ext_vector_type(8)));
typedef float f32x4 __attribute__((ext_vector_type(4)));

__device__ inline unsigned long long shfl_xor_u64(unsigned long long v, int off) {
    int lo = __shfl_xor((int)(unsigned)(v & 0xffffffffull), off, 64);
    int hi = __shfl_xor((int)(unsigned)(v >> 32), off, 64);
    return ((unsigned long long)(unsigned)hi << 32) | (unsigned)lo;
}

__device__ inline void gload16(const void* g, void* l) {
    __builtin_amdgcn_global_load_lds(
        (const __attribute__((address_space(1))) unsigned int*)g,
        (__attribute__((address_space(3))) unsigned int*)l, 16, 0, 0);
}

// ---------------- K0: mask + per-perspective inverse norms (fp32 exact) ----------------
__global__ void k_prep(const float* __restrict__ X, const int* __restrict__ lens,
                       const float* __restrict__ glw,
                       float* __restrict__ mask, float* __restrict__ invn)
{
    int row = blockIdx.x * 4 + (threadIdx.x >> 6);
    int lane = threadIdx.x & 63;
    if (row >= cB * cN) return;
    int b = row >> 9, n = row & (cN - 1);
    float s0 = 0.f, s1 = 0.f, s2 = 0.f, s3 = 0.f;
    const float* x = X + (long long)row * cIN;
    for (int d = lane; d < cIN; d += 64) {
        float xv = x[d];
        float x2 = xv * xv;
        float w0 = glw[0 * cIN + d], w1 = glw[1 * cIN + d];
        float w2 = glw[2 * cIN + d], w3 = glw[3 * cIN + d];
        s0 += x2 * w0 * w0;
        s1 += x2 * w1 * w1;
        s2 += x2 * w2 * w2;
        s3 += x2 * w3 * w3;
    }
    #pragma unroll
    for (int off = 32; off; off >>= 1) {
        s0 += __shfl_xor(s0, off, 64);
        s1 += __shfl_xor(s1, off, 64);
        s2 += __shfl_xor(s2, off, 64);
        s3 += __shfl_xor(s3, off, 64);
    }
    if (lane == 0) {
        mask[row] = (n < lens[b]) ? 1.0f : 0.0f;
        invn[0 * (cB * cN) + row] = 1.0f / fmaxf(sqrtf(s0), cVSN);
        invn[1 * (cB * cN) + row] = 1.0f / fmaxf(sqrtf(s1), cVSN);
        invn[2 * (cB * cN) + row] = 1.0f / fmaxf(sqrtf(s2), cVSN);
        invn[3 * (cB * cN) + row] = 1.0f / fmaxf(sqrtf(s3), cVSN);
    }
}

// ---------------- K0b: build f16 split/weighted arrays ----------------
// Arrays (each [B*N][KP] f16): t=0 XH, 1 XL, 2..5 W_p = f16(w_p^2 * x)
__global__ void k_split(const float* __restrict__ X, const float* __restrict__ glw,
                        _Float16* __restrict__ F16)
{
    int gid = blockIdx.x * 256 + threadIdx.x;   // over rows * (KP/8)
    int row = gid / (KP / 8);
    int g8  = gid % (KP / 8);
    int k   = g8 * 8;
    f16x8 vh, vl, w1v, w2v, w3v, w4v;
    if (k < cIN) {
        const float* x = X + (long long)row * cIN + k;
        #pragma unroll
        for (int e = 0; e < 8; ++e) {
            float xv = x[e];
            f16 h = (f16)xv;
            f16 l = (f16)(xv - (float)h);
            float ww1 = glw[0 * cIN + k + e]; ww1 *= ww1;
            float ww2 = glw[1 * cIN + k + e]; ww2 *= ww2;
            float ww3 = glw[2 * cIN + k + e]; ww3 *= ww3;
            float ww4 = glw[3 * cIN + k + e]; ww4 *= ww4;
            vh[e] = h; vl[e] = l;
            w1v[e] = (f16)(ww1 * xv);
            w2v[e] = (f16)(ww2 * xv);
            w3v[e] = (f16)(ww3 * xv);
            w4v[e] = (f16)(ww4 * xv);
        }
    } else {
        #pragma unroll
        for (int e = 0; e < 8; ++e) { vh[e] = (f16)0.f; vl[e] = (f16)0.f;
            w1v[e] = (f16)0.f; w2v[e] = (f16)0.f; w3v[e] = (f16)0.f; w4v[e] = (f16)0.f; }
    }
    size_t base = (size_t)row * KP + k;
    *(f16x8*)(F16 + 0 * ARRSZ + base) = vh;
    *(f16x8*)(F16 + 1 * ARRSZ + base) = vl;
    *(f16x8*)(F16 + 2 * ARRSZ + base) = w1v;
    *(f16x8*)(F16 + 3 * ARRSZ + base) = w2v;
    *(f16x8*)(F16 + 4 * ARRSZ + base) = w3v;
    *(f16x8*)(F16 + 5 * ARRSZ + base) = w4v;
}

// ---------------- K1: MFMA similarity. G0 = split-f16 X·X^T (fp32-accurate),
// RA = sparsified mean of 4 weighted cosines (plain f16). ----------------
__global__ __launch_bounds__(256, 2) void k_sim_mfma(
    const _Float16* __restrict__ F16,
    const float* __restrict__ maskA, const float* __restrict__ invn,
    float* __restrict__ G0, float* __restrict__ RA)
{
    const int b = blockIdx.z;
    const int n0 = blockIdx.y * 64, m0 = blockIdx.x * 64;
    const int t = threadIdx.x;
    const int w = t >> 6, lane = t & 63;
    const int wr = w >> 1, wc = w & 1;
    const int lr = lane & 15, lc = lane >> 4;

    // LDS: 8 tiles of [64 rows][4 slots][8 f16]; slot s holds k-chunk (s ^ (row&3))
    __shared__ _Float16 lds[16384];
    const f16x8* L8 = (const f16x8*)lds;

    f32x4 accG[2][2], acc1[2][2], acc2[2][2], acc3[2][2], acc4[2][2];
    #pragma unroll
    for (int i = 0; i < 2; ++i)
        #pragma unroll
        for (int j = 0; j < 2; ++j) {
            accG[i][j] = (f32x4)0.f; acc1[i][j] = (f32x4)0.f; acc2[i][j] = (f32x4)0.f;
            acc3[i][j] = (f32x4)0.f; acc4[i][j] = (f32x4)0.f;
        }

    const size_t rowBaseB = (size_t)b * cN;

    for (int pan = 0; pan < KP / 32; ++pan) {
        const int kk0 = pan * 32;
        // ---- stage 8 tiles (6 A-side from n0, 2 B-side = XH/XL from m0) ----
        #pragma unroll
        for (int q = 0; q < 8; ++q) {
            int c   = w * 8 + q;              // chunk 0..31 (uniform per wave)
            int tt  = c >> 2;                 // tile 0..7
            int row = (c & 3) * 16 + (lane >> 2);
            int kcs = lane & 3;
            int kcg = kcs ^ (row & 3);
            int ta  = (tt < 6) ? tt : (tt - 6);
            int rb  = (tt < 6) ? n0 : m0;
            const _Float16* g = F16 + (size_t)ta * ARRSZ
                              + (rowBaseB + rb + row) * (size_t)KP + kk0 + kcg * 8;
            gload16(g, (void*)&lds[(size_t)c * 64 * 8]);
        }
        __syncthreads();

        // ---- fragments ----
        f16x8 aH[2], aL[2], a1[2], a2[2], a3[2], a4[2];
        #pragma unroll
        for (int i = 0; i < 2; ++i) {
            int r = wr * 32 + i * 16 + lr;
            int s = r * 4 + (lc ^ (r & 3));
            aH[i] = L8[0 * 256 + s];
            aL[i] = L8[1 * 256 + s];
            a1[i] = L8[2 * 256 + s];
            a2[i] = L8[3 * 256 + s];
            a3[i] = L8[4 * 256 + s];
            a4[i] = L8[5 * 256 + s];
        }
        f16x8 bH[2], bL[2];
        #pragma unroll
        for (int j = 0; j < 2; ++j) {
            int r = wc * 32 + j * 16 + lr;
            int s = r * 4 + (lc ^ (r & 3));
            bH[j] = L8[6 * 256 + s];
            bL[j] = L8[7 * 256 + s];
        }

        // ---- MFMAs: 7 passes ----
        #pragma unroll
        for (int i = 0; i < 2; ++i)
            #pragma unroll
            for (int j = 0; j < 2; ++j) {
                accG[i][j] = __builtin_amdgcn_mfma_f32_16x16x32_f16(aH[i], bH[j], accG[i][j], 0, 0, 0);
                accG[i][j] = __builtin_amdgcn_mfma_f32_16x16x32_f16(aH[i], bL[j], accG[i][j], 0, 0, 0);
                accG[i][j] = __builtin_amdgcn_mfma_f32_16x16x32_f16(aL[i], bH[j], accG[i][j], 0, 0, 0);
                acc1[i][j] = __builtin_amdgcn_mfma_f32_16x16x32_f16(a1[i], bH[j], acc1[i][j], 0, 0, 0);
                acc2[i][j] = __builtin_amdgcn_mfma_f32_16x16x32_f16(a2[i], bH[j], acc2[i][j], 0, 0, 0);
                acc3[i][j] = __builtin_amdgcn_mfma_f32_16x16x32_f16(a3[i], bH[j], acc3[i][j], 0, 0, 0);
                acc4[i][j] = __builtin_amdgcn_mfma_f32_16x16x32_f16(a4[i], bH[j], acc4[i][j], 0, 0, 0);
            }
        __syncthreads();
    }

    // ---- epilogue: mask, cosine-normalize, sparsify, store ----
    const int NB = cB * cN;
    #pragma unroll
    for (int i = 0; i < 2; ++i) {
        #pragma unroll
        for (int j = 0; j < 2; ++j) {
            int m = m0 + wc * 32 + j * 16 + lr;           // col = lane&15
            size_t rowm = rowBaseB + m;
            float mskm = maskA[rowm];
            float im0 = invn[0 * NB + rowm], im1 = invn[1 * NB + rowm];
            float im2 = invn[2 * NB + rowm], im3 = invn[3 * NB + rowm];
            #pragma unroll
            for (int v = 0; v < 4; ++v) {
                int n = n0 + wr * 32 + i * 16 + lc * 4 + v; // row = (lane>>4)*4+v
                size_t rown = rowBaseB + n;
                float mk = maskA[rown] * mskm;
                float g = accG[i][j][v] * mk;
                float s = 0.25f * (acc1[i][j][v] * invn[0 * NB + rown] * im0
                                 + acc2[i][j][v] * invn[1 * NB + rown] * im1
                                 + acc3[i][j][v] * invn[2 * NB + rown] * im2
                                 + acc4[i][j][v] * invn[3 * NB + rown] * im3) * mk;
                float rv = (s > cEPS) ? s : 0.f;
                G0[rown * cN + m] = g;
                RA[rown * cN + m] = rv;
            }
        }
    }
}

// ---------------- K1b: row sums of sparsified RA ----------------
__global__ void k_rowsum(const float* __restrict__ RA, float* __restrict__ rowsum)
{
    int row = blockIdx.x * 4 + (threadIdx.x >> 6);
    int lane = threadIdx.x & 63;
    const float* r = RA + (long long)row * cN;
    float s = 0.f;
    #pragma unroll
    for (int k = 0; k < 8; ++k) s += r[lane + 64 * k];
    #pragma unroll
    for (int off = 32; off; off >>= 1) s += __shfl_xor(s, off, 64);
    if (lane == 0) rowsum[row] = fmaxf(s, cVSN);
}

// ---------------- K2: per-row top-10 (value desc, index asc) ----------------
__global__ void k_topk(const float* __restrict__ G0, const float* __restrict__ mask,
                       int* __restrict__ kidx, float* __restrict__ rinv)
{
    int row = blockIdx.x * 4 + (threadIdx.x >> 6);
    int lane = threadIdx.x & 63;
    int b = row >> 9, n = row & (cN - 1);
    const float* g = G0 + (long long)row * cN;
    unsigned long long key[8];
    #pragma unroll
    for (int k = 0; k < 8; ++k) {
        int col = lane + 64 * k;
        float v = g[col];
        unsigned u = __float_as_uint(v);
        u ^= (unsigned)(((int)u >> 31)) | 0x80000000u;
        key[k] = ((unsigned long long)u << 32) | (unsigned)(cN - 1 - col);
    }
    float cnt = 0.f;
    long long mbase = (long long)b * cN;
    for (int r = 0; r < cKNN; ++r) {
        unsigned long long best = 0ull;
        #pragma unroll
        for (int k = 0; k < 8; ++k) best = (key[k] > best) ? key[k] : best;
        #pragma unroll
        for (int off = 32; off; off >>= 1) {
            unsigned long long o = shfl_xor_u64(best, off);
            if (o > best) best = o;
        }
        int col = (cN - 1) - (int)(best & 0xffffffffull);
        #pragma unroll
        for (int k = 0; k < 8; ++k) if (key[k] == best) key[k] = 0ull;
        if (lane == 0) {
            kidx[row * cKNN + r] = col;
            cnt += mask[mbase + col];
        }
    }
    if (lane == 0) {
        float mk = mask[mbase + n];
        rinv[row] = (mk > 0.f) ? rsqrtf(fmaxf(cnt, cVSN)) : 0.f;
    }
}

// ---------------- K3: final adjacency assembly ----------------
__global__ void k_adj(const float* __restrict__ RA, const float* __restrict__ rowsum,
                      const float* __restrict__ rinv, const int* __restrict__ kidx,
                      float* __restrict__ ADJ)
{
    int row = blockIdx.x;
    int t = threadIdx.x;  // 256
    __shared__ int sidx[cKNN];
    __shared__ float srv[cKNN];
    long long bbase = (long long)(row & ~(cN - 1));
    if (t < cKNN) {
        int c = kidx[row * cKNN + t];
        sidx[t] = c;
        srv[t] = rinv[bbase + c];
    }
    __syncthreads();
    float rn = rinv[row];
    float inv_rs = 1.0f / rowsum[row];
    long long base = (long long)row * cN;
    #pragma unroll
    for (int mi = 0; mi < 2; ++mi) {
        int m = t + mi * 256;
        float v = (1.0f - cSKIP) * RA[base + m] * inv_rs;
        #pragma unroll
        for (int k = 0; k < cKNN; ++k)
            if (m == sidx[k]) v += cSKIP * rn * srv[k];
        ADJ[base + m] = v;
    }
}

// ---------------- Generic tiled fp32 GEMM: C = A@B (+bias)(relu), batched ----------------
template<bool RELU, bool BIAS>
__global__ __launch_bounds__(256) void k_gemm(
    const float* __restrict__ A, const float* __restrict__ Bm,
    const float* __restrict__ bias, float* __restrict__ C,
    int M, int Nc, int K,
    long long sA, long long sB, long long sC)
{
    const int bz = blockIdx.z;
    A += (long long)bz * sA;
    Bm += (long long)bz * sB;
    C += (long long)bz * sC;
    const int bm = blockIdx.y * 64, bn = blockIdx.x * 64;
    __shared__ float As[16][68];   // [k][row]
    __shared__ float Bs[16][68];   // [k][col]
    const int t = threadIdx.x, tx = t & 15, ty = t >> 4;
    float acc[4][4];
    #pragma unroll
    for (int i = 0; i < 4; ++i)
        #pragma unroll
        for (int j = 0; j < 4; ++j) acc[i][j] = 0.f;

    for (int k0 = 0; k0 < K; k0 += 16) {
        #pragma unroll
        for (int i = 0; i < 4; ++i) {
            int e = t + i * 256;
            { int r = e >> 4, c = e & 15;
              As[c][r] = A[(long long)(bm + r) * K + k0 + c]; }
            { int r = e >> 6, c = e & 63;
              Bs[r][c] = Bm[(long long)(k0 + r) * Nc + bn + c]; }
        }
        __syncthreads();
        #pragma unroll
        for (int kk = 0; kk < 16; ++kk) {
            float a[4], bb[4];
            #pragma unroll
            for (int i = 0; i < 4; ++i) a[i] = As[kk][ty * 4 + i];
            #pragma unroll
            for (int j = 0; j < 4; ++j) bb[j] = Bs[kk][tx * 4 + j];
            #pragma unroll
            for (int i = 0; i < 4; ++i)
                #pragma unroll
                for (int j = 0; j < 4; ++j)
                    acc[i][j] += a[i] * bb[j];
        }
        __syncthreads();
    }
    #pragma unroll
    for (int i = 0; i < 4; ++i) {
        long long r = bm + ty * 4 + i;
        float ov[4];
        #pragma unroll
        for (int j = 0; j < 4; ++j) {
            float v = acc[i][j];
            if (BIAS) v += bias[bn + tx * 4 + j];
            if (RELU) v = fmaxf(v, 0.f);
            ov[j] = v;
        }
        *(float4*)(C + r * Nc + bn + tx * 4) = make_float4(ov[0], ov[1], ov[2], ov[3]);
    }
}

// ---------------- K5: maxpool + mention merge + final linear ----------------
__global__ void k_final(const float* __restrict__ nv, const int* __restrict__ mentions,
                        const float* __restrict__ lw, const float* __restrict__ lb,
                        float* __restrict__ out)
{
    int b = blockIdx.x;
    int t = threadIdx.x;            // 512
    int d = t & 127, g = t >> 7;    // 4 row-groups
    __shared__ float smx[4][128], sa1[4][128], sa2[4][128];
    int s1 = mentions[b * 4 + 0], e1 = mentions[b * 4 + 1];
    int s2 = mentions[b * 4 + 2], e2 = mentions[b * 4 + 3];
    const float* p = nv + (long long)b * cN * cOUT;
    float mx = -INFINITY, a1 = 0.f, a2 = 0.f;
    for (int n = g * 128; n < (g + 1) * 128; ++n) {
        float v = p[n * cOUT + d];
        mx = fmaxf(mx, v);
        if (n >= s1 && n <= e1) a1 += v;
        if (n >= s2 && n <= e2) a2 += v;
    }
    smx[g][d] = mx; sa1[g][d] = a1; sa2[g][d] = a2;
    __syncthreads();
    if (t < 128) {
        float m2 = fmaxf(fmaxf(smx[0][t], smx[1][t]), fmaxf(smx[2][t], smx[3][t]));
        float b1s = sa1[0][t] + sa1[1][t] + sa1[2][t] + sa1[3][t];
        float b2s = sa2[0][t] + sa2[1][t] + sa2[2][t] + sa2[3][t];
        smx[0][t] = m2 + b1s / (float)(e1 - s1 + 1) + b2s / (float)(e2 - s2 + 1);
    }
    __syncthreads();
    if (t < cNREL) {
        float s = lb[t];
        for (int dd = 0; dd < cOUT; ++dd) s += smx[0][dd] * lw[dd * cNREL + t];
        out[b * cNREL + t] = s;
    }
}

extern "C" void kernel_launch(void* const* d_in, const int* in_sizes, int n_in,
                              void* d_out, int out_size, void* d_ws, size_t ws_size,
                              hipStream_t stream)
{
    const float* context = (const float*)d_in[0];
    const int*   lens    = (const int*)d_in[1];
    const int*   ments   = (const int*)d_in[2];
    const float* w_enc   = (const float*)d_in[3];
    const float* b_enc   = (const float*)d_in[4];
    const float* glw     = (const float*)d_in[5];
    const float* w1      = (const float*)d_in[6];
    const float* b1      = (const float*)d_in[7];
    const float* w2      = (const float*)d_in[8];
    const float* b2      = (const float*)d_in[9];
    const float* lw      = (const float*)d_in[10];
    const float* lb      = (const float*)d_in[11];
    float* out = (float*)d_out;

    // ---- workspace layout ----
    // F16 region (6 arrays of [B*N][KP] f16) is later reused for enc/t1/h/t2/nv (fp32).
    _Float16* F16 = (_Float16*)d_ws;
    const size_t F16_floats = (6 * ARRSZ * sizeof(_Float16)) / sizeof(float); // 30,670,848
    float* ws = (float*)d_ws;
    float* ADJ  = ws + F16_floats;                  // 48*512*512, holds G0 then final adj
    float* RA   = ADJ + (size_t)cB * cN * cN;       // 48*512*512
    float* invn = RA + (size_t)cB * cN * cN;        // 4*48*512
    float* maskA = invn + 4 * (size_t)cB * cN;      // 48*512
    float* rinv  = maskA + (size_t)cB * cN;         // 48*512
    float* rowsum = rinv + (size_t)cB * cN;         // 48*512
    int*   kidx = (int*)(rowsum + (size_t)cB * cN); // 48*512*10
    // reuse F16 region after k_sim_mfma:
    float* enc = (float*)d_ws;                      // 48*512*256
    float* t1  = enc + (size_t)cB * cN * cENC;      // 48*512*256
    float* h   = t1 + (size_t)cB * cN * cENC;       // 48*512*128
    float* t2  = h + (size_t)cB * cN * cHID;        // 48*512*128
    float* nv  = t2 + (size_t)cB * cN * cHID;       // 48*512*128

    k_prep<<<cB * cN / 4, 256, 0, stream>>>(context, lens, glw, maskA, invn);
    k_split<<<(cB * cN * (KP / 8)) / 256, 256, 0, stream>>>(context, glw, F16);
    k_sim_mfma<<<dim3(cN / 64, cN / 64, cB), 256, 0, stream>>>(F16, maskA, invn, ADJ, RA);
    k_rowsum<<<cB * cN / 4, 256, 0, stream>>>(RA, rowsum);
    k_topk<<<cB * cN / 4, 256, 0, stream>>>(ADJ, maskA, kidx, rinv);
    k_adj<<<cB * cN, 256, 0, stream>>>(RA, rowsum, rinv, kidx, ADJ);

    // enc = context @ w_enc + b_enc
    k_gemm<false, true><<<dim3(cENC / 64, (cB * cN) / 64, 1), 256, 0, stream>>>(
        context, w_enc, b_enc, enc, cB * cN, cENC, cIN, 0, 0, 0);
    // t1 = adj @ enc  (batched)
    k_gemm<false, false><<<dim3(cENC / 64, cN / 64, cB), 256, 0, stream>>>(
        ADJ, enc, nullptr, t1, cN, cENC, cN,
        (long long)cN * cN, (long long)cN * cENC, (long long)cN * cENC);
    // h = relu(t1 @ w1 + b1)
    k_gemm<true, true><<<dim3(cHID / 64, (cB * cN) / 64, 1), 256, 0, stream>>>(
        t1, w1, b1, h, cB * cN, cHID, cENC, 0, 0, 0);
    // t2 = adj @ h  (batched)
    k_gemm<false, false><<<dim3(cHID / 64, cN / 64, cB), 256, 0, stream>>>(
        ADJ, h, nullptr, t2, cN, cHID, cN,
        (long long)cN * cN, (long long)cN * cHID, (long long)cN * cHID);
    // nv = t2 @ w2 + b2
    k_gemm<false, true><<<dim3(cOUT / 64, (cB * cN) / 64, 1), 256, 0, stream>>>(
        t2, w2, b2, nv, cB * cN, cOUT, cHID, 0, 0, 0);

    k_final<<<cB, 512, 0, stream>>>(nv, ments, lw, lb, out);
}

// Round 3
// 415.916 us; speedup vs baseline: 3.1675x; 1.4742x over previous
//
#include <hip/hip_runtime.h>
#include <math.h>

// Problem constants
constexpr int cB = 48, cN = 512, cIN = 400;
constexpr int cENC = 256, cHID = 128, cOUT = 128, cNREL = 53;
constexpr int cKNN = 10;
constexpr float cVSN = 1e-12f;
constexpr float cEPS = 0.3f;

constexpr int KP = 416;                        // cIN padded to multiple of 32
constexpr size_t ARRSZ = (size_t)cB * cN * KP; // elems per f16 array (10,223,616)
constexpr int NBN = cB * cN;                   // 24576 rows
constexpr size_t NADJ = (size_t)cB * cN * cN;  // 12,582,912
constexpr size_t NE1 = (size_t)NBN * 128;      // 3,145,728

typedef _Float16 f16;
typedef _Float16 f16x8 __attribute__((ext_vector_type(8)));
typedef float f32x4 __attribute__((ext_vector_type(4)));

__device__ inline unsigned long long shfl_xor_u64(unsigned long long v, int off) {
    int lo = __shfl_xor((int)(unsigned)(v & 0xffffffffull), off, 64);
    int hi = __shfl_xor((int)(unsigned)(v >> 32), off, 64);
    return ((unsigned long long)(unsigned)hi << 32) | (unsigned)lo;
}

__device__ inline void gload16(const void* g, void* l) {
    __builtin_amdgcn_global_load_lds(
        (const __attribute__((address_space(1))) unsigned int*)g,
        (__attribute__((address_space(3))) unsigned int*)l, 16, 0, 0);
}

// ---------------- K0: fused mask/inv-norms + f16 split/weighted arrays ----------------
// F16 arrays (each [B*N][KP]): 0=XH, 1=XL, 2..5 = W_p = f16(w_p^2 * x)
__global__ void k_prep2(const float* __restrict__ X, const int* __restrict__ lens,
                        const float* __restrict__ glw,
                        float* __restrict__ mask, float* __restrict__ invn,
                        f16* __restrict__ F16)
{
    int row = blockIdx.x * 4 + (threadIdx.x >> 6);
    int lane = threadIdx.x & 63;
    int b = row >> 9, n = row & (cN - 1);
    const float* x = X + (long long)row * cIN;
    float s0 = 0.f, s1 = 0.f, s2 = 0.f, s3 = 0.f;
    if (lane < 52) {
        int k = lane * 8;
        f16x8 vh, vl, w1v, w2v, w3v, w4v;
        #pragma unroll
        for (int e = 0; e < 8; ++e) {
            int d = k + e;
            float xv = (d < cIN) ? x[d] : 0.f;
            float g0 = (d < cIN) ? glw[0 * cIN + d] : 0.f;
            float g1 = (d < cIN) ? glw[1 * cIN + d] : 0.f;
            float g2 = (d < cIN) ? glw[2 * cIN + d] : 0.f;
            float g3 = (d < cIN) ? glw[3 * cIN + d] : 0.f;
            float ww0 = g0 * g0, ww1 = g1 * g1, ww2 = g2 * g2, ww3 = g3 * g3;
            float x2 = xv * xv;
            s0 += x2 * ww0; s1 += x2 * ww1; s2 += x2 * ww2; s3 += x2 * ww3;
            f16 hh = (f16)xv;
            vh[e] = hh; vl[e] = (f16)(xv - (float)hh);
            w1v[e] = (f16)(ww0 * xv);
            w2v[e] = (f16)(ww1 * xv);
            w3v[e] = (f16)(ww2 * xv);
            w4v[e] = (f16)(ww3 * xv);
        }
        size_t base = (size_t)row * KP + k;
        *(f16x8*)(F16 + 0 * ARRSZ + base) = vh;
        *(f16x8*)(F16 + 1 * ARRSZ + base) = vl;
        *(f16x8*)(F16 + 2 * ARRSZ + base) = w1v;
        *(f16x8*)(F16 + 3 * ARRSZ + base) = w2v;
        *(f16x8*)(F16 + 4 * ARRSZ + base) = w3v;
        *(f16x8*)(F16 + 5 * ARRSZ + base) = w4v;
    }
    #pragma unroll
    for (int off = 32; off; off >>= 1) {
        s0 += __shfl_xor(s0, off, 64);
        s1 += __shfl_xor(s1, off, 64);
        s2 += __shfl_xor(s2, off, 64);
        s3 += __shfl_xor(s3, off, 64);
    }
    if (lane == 0) {
        mask[row] = (n < lens[b]) ? 1.0f : 0.0f;
        invn[0 * NBN + row] = 1.0f / fmaxf(sqrtf(s0), cVSN);
        invn[1 * NBN + row] = 1.0f / fmaxf(sqrtf(s1), cVSN);
        invn[2 * NBN + row] = 1.0f / fmaxf(sqrtf(s2), cVSN);
        invn[3 * NBN + row] = 1.0f / fmaxf(sqrtf(s3), cVSN);
    }
}

// ---------------- K0b: fused weight prep ----------------
// Wc1T[o][d] = (w_enc @ w1)^T split f16 (d padded to 416); w2T split; bc1p = b_enc@w1
__global__ void k_prepw(const float* __restrict__ w_enc, const float* __restrict__ w1,
                        const float* __restrict__ b_enc, const float* __restrict__ w2,
                        f16* __restrict__ wc1H, f16* __restrict__ wc1L,
                        float* __restrict__ bc1p,
                        f16* __restrict__ w2tH, f16* __restrict__ w2tL)
{
    int d = blockIdx.x;      // 0..416
    int o = threadIdx.x;     // 0..127
    if (d < KP) {
        float acc = 0.f;
        if (d < cIN)
            for (int e = 0; e < cENC; ++e) acc += w_enc[(size_t)d * cENC + e] * w1[(size_t)e * cHID + o];
        f16 h = (f16)acc;
        wc1H[(size_t)o * KP + d] = h;
        wc1L[(size_t)o * KP + d] = (f16)(acc - (float)h);
        if (d < cHID) {
            float v = w2[(size_t)d * cOUT + o];
            f16 h2 = (f16)v;
            w2tH[(size_t)o * cHID + d] = h2;
            w2tL[(size_t)o * cHID + d] = (f16)(v - (float)h2);
        }
    } else {
        float acc = 0.f;
        for (int e = 0; e < cENC; ++e) acc += b_enc[e] * w1[(size_t)e * cHID + o];
        bc1p[o] = acc;
    }
}

// ---------------- K1: MFMA similarity ----------------
__global__ __launch_bounds__(256, 2) void k_sim_mfma(
    const f16* __restrict__ F16,
    const float* __restrict__ maskA, const float* __restrict__ invn,
    float* __restrict__ G0, f16* __restrict__ RAh)
{
    // bijective XCD swizzle: keep all 64 blocks of a batch on one XCD
    int L = blockIdx.x + (blockIdx.y << 3) + (blockIdx.z << 6);
    int xcd = L & 7, j = L >> 3;
    int work = xcd * 384 + j;
    const int b = work >> 6;
    int rem = work & 63;
    const int n0 = (rem >> 3) * 64, m0 = (rem & 7) * 64;

    const int t = threadIdx.x;
    const int w = t >> 6, lane = t & 63;
    const int wr = w >> 1, wc = w & 1;
    const int lr = lane & 15, lc = lane >> 4;

    __shared__ f16 lds[16384];  // 8 tiles x [64 rows][4 slots][8 f16]
    const f16x8* L8 = (const f16x8*)lds;

    f32x4 accG[2][2], acc1[2][2], acc2[2][2], acc3[2][2], acc4[2][2];
    #pragma unroll
    for (int i = 0; i < 2; ++i)
        #pragma unroll
        for (int jj = 0; jj < 2; ++jj) {
            accG[i][jj] = (f32x4)0.f; acc1[i][jj] = (f32x4)0.f; acc2[i][jj] = (f32x4)0.f;
            acc3[i][jj] = (f32x4)0.f; acc4[i][jj] = (f32x4)0.f;
        }

    const size_t rowBaseB = (size_t)b * cN;

    for (int pan = 0; pan < KP / 32; ++pan) {
        const int kk0 = pan * 32;
        #pragma unroll
        for (int q = 0; q < 8; ++q) {
            int c   = w * 8 + q;              // chunk 0..31
            int tt  = c >> 2;                 // tile 0..7
            int row = (c & 3) * 16 + (lane >> 2);
            int kcs = lane & 3;
            int kcg = kcs ^ (row & 3) ^ ((row >> 2) & 3);
            int ta  = (tt < 6) ? tt : (tt - 6);
            int rb  = (tt < 6) ? n0 : m0;
            const f16* g = F16 + (size_t)ta * ARRSZ
                         + (rowBaseB + rb + row) * (size_t)KP + kk0 + kcg * 8;
            gload16(g, (void*)&lds[(size_t)c * 64 * 8]);
        }
        __syncthreads();

        f16x8 aH[2], aL[2], a1[2], a2[2], a3[2], a4[2];
        #pragma unroll
        for (int i = 0; i < 2; ++i) {
            int r = wr * 32 + i * 16 + lr;
            int s = r * 4 + (lc ^ (r & 3) ^ ((r >> 2) & 3));
            aH[i] = L8[0 * 256 + s];
            aL[i] = L8[1 * 256 + s];
            a1[i] = L8[2 * 256 + s];
            a2[i] = L8[3 * 256 + s];
            a3[i] = L8[4 * 256 + s];
            a4[i] = L8[5 * 256 + s];
        }
        f16x8 bH[2], bL[2];
        #pragma unroll
        for (int jj = 0; jj < 2; ++jj) {
            int r = wc * 32 + jj * 16 + lr;
            int s = r * 4 + (lc ^ (r & 3) ^ ((r >> 2) & 3));
            bH[jj] = L8[6 * 256 + s];
            bL[jj] = L8[7 * 256 + s];
        }

        #pragma unroll
        for (int i = 0; i < 2; ++i)
            #pragma unroll
            for (int jj = 0; jj < 2; ++jj) {
                accG[i][jj] = __builtin_amdgcn_mfma_f32_16x16x32_f16(aH[i], bH[jj], accG[i][jj], 0, 0, 0);
                accG[i][jj] = __builtin_amdgcn_mfma_f32_16x16x32_f16(aH[i], bL[jj], accG[i][jj], 0, 0, 0);
                accG[i][jj] = __builtin_amdgcn_mfma_f32_16x16x32_f16(aL[i], bH[jj], accG[i][jj], 0, 0, 0);
                acc1[i][jj] = __builtin_amdgcn_mfma_f32_16x16x32_f16(a1[i], bH[jj], acc1[i][jj], 0, 0, 0);
                acc2[i][jj] = __builtin_amdgcn_mfma_f32_16x16x32_f16(a2[i], bH[jj], acc2[i][jj], 0, 0, 0);
                acc3[i][jj] = __builtin_amdgcn_mfma_f32_16x16x32_f16(a3[i], bH[jj], acc3[i][jj], 0, 0, 0);
                acc4[i][jj] = __builtin_amdgcn_mfma_f32_16x16x32_f16(a4[i], bH[jj], acc4[i][jj], 0, 0, 0);
            }
        __syncthreads();
    }

    // epilogue: mask, cosine-normalize, sparsify; NT stores
    #pragma unroll
    for (int i = 0; i < 2; ++i) {
        #pragma unroll
        for (int jj = 0; jj < 2; ++jj) {
            int m = m0 + wc * 32 + jj * 16 + lr;
            size_t rowm = rowBaseB + m;
            float mskm = maskA[rowm];
            float im0 = invn[0 * NBN + rowm], im1 = invn[1 * NBN + rowm];
            float im2 = invn[2 * NBN + rowm], im3 = invn[3 * NBN + rowm];
            #pragma unroll
            for (int v = 0; v < 4; ++v) {
                int n = n0 + wr * 32 + i * 16 + lc * 4 + v;
                size_t rown = rowBaseB + n;
                float mk = maskA[rown] * mskm;
                float g = accG[i][jj][v] * mk;
                float s = 0.25f * (acc1[i][jj][v] * invn[0 * NBN + rown] * im0
                                 + acc2[i][jj][v] * invn[1 * NBN + rown] * im1
                                 + acc3[i][jj][v] * invn[2 * NBN + rown] * im2
                                 + acc4[i][jj][v] * invn[3 * NBN + rown] * im3) * mk;
                float rv = (s > cEPS) ? s : 0.f;
                __builtin_nontemporal_store(g, &G0[rown * cN + m]);
                __builtin_nontemporal_store((f16)rv, &RAh[rown * cN + m]);
            }
        }
    }
}

// ---------------- K2: per-row top-10 (value desc, index asc) ----------------
__global__ void k_topk(const float* __restrict__ G0, const float* __restrict__ mask,
                       int* __restrict__ kidx, float* __restrict__ rinv)
{
    int row = blockIdx.x * 4 + (threadIdx.x >> 6);
    int lane = threadIdx.x & 63;
    int b = row >> 9, n = row & (cN - 1);
    const float* g = G0 + (long long)row * cN;
    unsigned long long key[8];
    #pragma unroll
    for (int k = 0; k < 8; ++k) {
        int col = lane + 64 * k;
        float v = __builtin_nontemporal_load(&g[col]);
        unsigned u = __float_as_uint(v);
        u ^= (unsigned)(((int)u >> 31)) | 0x80000000u;
        key[k] = ((unsigned long long)u << 32) | (unsigned)(cN - 1 - col);
    }
    float cnt = 0.f;
    long long mbase = (long long)b * cN;
    for (int r = 0; r < cKNN; ++r) {
        unsigned long long best = 0ull;
        #pragma unroll
        for (int k = 0; k < 8; ++k) best = (key[k] > best) ? key[k] : best;
        #pragma unroll
        for (int off = 32; off; off >>= 1) {
            unsigned long long o = shfl_xor_u64(best, off);
            if (o > best) best = o;
        }
        int col = (cN - 1) - (int)(best & 0xffffffffull);
        #pragma unroll
        for (int k = 0; k < 8; ++k) if (key[k] == best) key[k] = 0ull;
        if (lane == 0) {
            kidx[row * cKNN + r] = col;
            cnt += mask[mbase + col];
        }
    }
    if (lane == 0) {
        float mk = mask[mbase + n];
        rinv[row] = (mk > 0.f) ? rsqrtf(fmaxf(cnt, cVSN)) : 0.f;
    }
}

// ---------------- K3: adjacency assembly (fused rowsum, split-f16 out, adjrs) -------
__global__ void k_adj2(const f16* __restrict__ RAh, const float* __restrict__ rinv,
                       const int* __restrict__ kidx,
                       f16* __restrict__ adjH, f16* __restrict__ adjL,
                       float* __restrict__ adjrs)
{
    int row = blockIdx.x;
    int t = threadIdx.x;  // 256
    int w = t >> 6, lane = t & 63;
    __shared__ int sidx[cKNN];
    __shared__ float srv[cKNN];
    __shared__ float red[4];
    long long bbase = (long long)(row & ~(cN - 1));
    if (t < cKNN) {
        int c = kidx[row * cKNN + t];
        sidx[t] = c;
        srv[t] = rinv[bbase + c];
    }
    long long base = (long long)row * cN;
    float ra0 = (float)__builtin_nontemporal_load(&RAh[base + t]);
    float ra1 = (float)__builtin_nontemporal_load(&RAh[base + t + 256]);
    float s = ra0 + ra1;
    #pragma unroll
    for (int off = 32; off; off >>= 1) s += __shfl_xor(s, off, 64);
    if (lane == 0) red[w] = s;
    __syncthreads();
    float rsum = red[0] + red[1] + red[2] + red[3];
    float inv_rs = 1.0f / fmaxf(rsum, cVSN);
    float rn = rinv[row];
    float osum = 0.f;
    #pragma unroll
    for (int mi = 0; mi < 2; ++mi) {
        int m = t + mi * 256;
        float ra = mi ? ra1 : ra0;
        float v = 0.2f * ra * inv_rs;
        #pragma unroll
        for (int k = 0; k < cKNN; ++k)
            if (m == sidx[k]) v += 0.8f * rn * srv[k];
        f16 hh = (f16)v;
        adjH[base + m] = hh;
        adjL[base + m] = (f16)(v - (float)hh);
        osum += v;
    }
    #pragma unroll
    for (int off = 32; off; off >>= 1) osum += __shfl_xor(osum, off, 64);
    __syncthreads();
    if (lane == 0) red[w] = osum;
    __syncthreads();
    if (t == 0) adjrs[row] = red[0] + red[1] + red[2] + red[3];
}

// ---------------- Unified split-f16 MFMA GEMM ----------------
// C[M][128] = split3(A[M][K] @ B^T[128][K]); BM=64, BN=128, BK=32.
// BIAS: 0 none, 1 +biasv[col], 2 +adjrs[row]*bc1p[col]+biasv[col]
template<int BIAS, bool RELU, bool OSPLIT, bool OTRANS>
__global__ __launch_bounds__(256, 2) void k_gemm_sp(
    const f16* __restrict__ AH, const f16* __restrict__ AL,
    const f16* __restrict__ BHp, const f16* __restrict__ BLp,
    long long bStrideB, int K,
    const float* __restrict__ biasv, const float* __restrict__ bc1p,
    const float* __restrict__ adjrs,
    float* __restrict__ Cf, f16* __restrict__ CH, f16* __restrict__ CL)
{
    const int R0 = blockIdx.x * 64;
    const int bidx = R0 >> 9;
    const int t = threadIdx.x, w = t >> 6, lane = t & 63;
    const int wr = w >> 1, wc = w & 1, lr = lane & 15, lc = lane >> 4;
    __shared__ f16 lds[1536 * 8];   // 24 KB
    const f16x8* L8 = (const f16x8*)lds;
    const f16* Bh = BHp + (size_t)bidx * bStrideB;
    const f16* Bl = BLp + (size_t)bidx * bStrideB;

    f32x4 acc[2][4];
    #pragma unroll
    for (int i = 0; i < 2; ++i)
        #pragma unroll
        for (int jj = 0; jj < 4; ++jj) acc[i][jj] = (f32x4)0.f;

    for (int k0 = 0; k0 < K; k0 += 32) {
        #pragma unroll
        for (int q = 0; q < 6; ++q) {
            int e = q * 256 + w * 64 + lane;
            const f16* src;
            if (e < 512) {
                int ci = e & 255;
                int row = ci >> 2, slot = ci & 3;
                int kc = slot ^ (row & 3) ^ ((row >> 2) & 3);
                src = ((e < 256) ? AH : AL) + (size_t)(R0 + row) * K + k0 + kc * 8;
            } else {
                int ci = e & 511;
                int row = ci >> 2, slot = ci & 3;
                int kc = slot ^ (row & 3) ^ ((row >> 2) & 3);
                src = ((e < 1024) ? Bh : Bl) + (size_t)row * K + k0 + kc * 8;
            }
            gload16(src, (void*)&lds[(size_t)e * 8]);
        }
        __syncthreads();
        f16x8 aH[2], aL[2], bH[4], bL[4];
        #pragma unroll
        for (int i = 0; i < 2; ++i) {
            int r = wr * 32 + i * 16 + lr;
            int cell = r * 4 + (lc ^ (r & 3) ^ ((r >> 2) & 3));
            aH[i] = L8[cell];
            aL[i] = L8[256 + cell];
        }
        #pragma unroll
        for (int jj = 0; jj < 4; ++jj) {
            int r = wc * 64 + jj * 16 + lr;
            int cell = r * 4 + (lc ^ (r & 3) ^ ((r >> 2) & 3));
            bH[jj] = L8[512 + cell];
            bL[jj] = L8[1024 + cell];
        }
        #pragma unroll
        for (int i = 0; i < 2; ++i)
            #pragma unroll
            for (int jj = 0; jj < 4; ++jj) {
                acc[i][jj] = __builtin_amdgcn_mfma_f32_16x16x32_f16(aH[i], bH[jj], acc[i][jj], 0, 0, 0);
                acc[i][jj] = __builtin_amdgcn_mfma_f32_16x16x32_f16(aH[i], bL[jj], acc[i][jj], 0, 0, 0);
                acc[i][jj] = __builtin_amdgcn_mfma_f32_16x16x32_f16(aL[i], bH[jj], acc[i][jj], 0, 0, 0);
            }
        __syncthreads();
    }

    #pragma unroll
    for (int i = 0; i < 2; ++i)
        #pragma unroll
        for (int jj = 0; jj < 4; ++jj) {
            int col = wc * 64 + jj * 16 + lr;
            #pragma unroll
            for (int v = 0; v < 4; ++v) {
                int r = R0 + wr * 32 + i * 16 + lc * 4 + v;
                float val = acc[i][jj][v];
                if (BIAS == 1) val += biasv[col];
                if (BIAS == 2) val += adjrs[r] * bc1p[col] + biasv[col];
                if (RELU) val = fmaxf(val, 0.f);
                if (!OSPLIT) {
                    Cf[(size_t)r * 128 + col] = val;
                } else {
                    f16 hh = (f16)val;
                    f16 ll = (f16)(val - (float)hh);
                    size_t addr = OTRANS
                        ? ((size_t)(r >> 9) * 65536 + (size_t)col * 512 + (r & 511))
                        : ((size_t)r * 128 + col);
                    CH[addr] = hh;
                    CL[addr] = ll;
                }
            }
        }
}

// ---------------- K5: maxpool + mention merge + final linear ----------------
__global__ void k_final(const float* __restrict__ nv, const int* __restrict__ mentions,
                        const float* __restrict__ lw, const float* __restrict__ lb,
                        float* __restrict__ out)
{
    int b = blockIdx.x;
    int t = threadIdx.x;            // 512
    int d = t & 127, g = t >> 7;
    __shared__ float smx[4][128], sa1[4][128], sa2[4][128];
    int s1 = mentions[b * 4 + 0], e1 = mentions[b * 4 + 1];
    int s2 = mentions[b * 4 + 2], e2 = mentions[b * 4 + 3];
    const float* p = nv + (long long)b * cN * cOUT;
    float mx = -INFINITY, a1 = 0.f, a2 = 0.f;
    for (int n = g * 128; n < (g + 1) * 128; ++n) {
        float v = p[n * cOUT + d];
        mx = fmaxf(mx, v);
        if (n >= s1 && n <= e1) a1 += v;
        if (n >= s2 && n <= e2) a2 += v;
    }
    smx[g][d] = mx; sa1[g][d] = a1; sa2[g][d] = a2;
    __syncthreads();
    if (t < 128) {
        float m2 = fmaxf(fmaxf(smx[0][t], smx[1][t]), fmaxf(smx[2][t], smx[3][t]));
        float b1s = sa1[0][t] + sa1[1][t] + sa1[2][t] + sa1[3][t];
        float b2s = sa2[0][t] + sa2[1][t] + sa2[2][t] + sa2[3][t];
        smx[0][t] = m2 + b1s / (float)(e1 - s1 + 1) + b2s / (float)(e2 - s2 + 1);
    }
    __syncthreads();
    if (t < cNREL) {
        float s = lb[t];
        for (int dd = 0; dd < cOUT; ++dd) s += smx[0][dd] * lw[dd * cNREL + t];
        out[b * cNREL + t] = s;
    }
}

extern "C" void kernel_launch(void* const* d_in, const int* in_sizes, int n_in,
                              void* d_out, int out_size, void* d_ws, size_t ws_size,
                              hipStream_t stream)
{
    const float* context = (const float*)d_in[0];
    const int*   lens    = (const int*)d_in[1];
    const int*   ments   = (const int*)d_in[2];
    const float* w_enc   = (const float*)d_in[3];
    const float* b_enc   = (const float*)d_in[4];
    const float* glw     = (const float*)d_in[5];
    const float* w1      = (const float*)d_in[6];
    const float* b1      = (const float*)d_in[7];
    const float* w2      = (const float*)d_in[8];
    const float* b2      = (const float*)d_in[9];
    const float* lw      = (const float*)d_in[10];
    const float* lb      = (const float*)d_in[11];
    float* out = (float*)d_out;

    // ---- workspace layout ----
    f16* F16 = (f16*)d_ws;
    f16* XH = F16;
    f16* XL = F16 + ARRSZ;
    // W1..4 (arr2..5) region reused after k_sim:
    f16* adjH = F16 + 2 * ARRSZ;
    f16* adjL = adjH + NADJ;
    f16* E1tH = adjL + NADJ;
    f16* E1tL = E1tH + NE1;
    f16* hH   = E1tL + NE1;
    f16* hL   = hH + NE1;

    float* base2 = (float*)d_ws + 3 * ARRSZ;   // after 6 f16 arrays
    float* G0 = base2;                          // NADJ floats; reused after topk:
    f16* H2tH = (f16*)G0;
    f16* H2tL = H2tH + NE1;
    float* nv = G0 + NE1;                       // disjoint from H2t (NE1 floats)

    f16* RAh = (f16*)(G0 + NADJ);               // NADJ f16
    float* invn  = G0 + NADJ + NADJ / 2;        // 4*NBN
    float* maskA = invn + 4 * NBN;
    float* rinv  = maskA + NBN;
    float* adjrs = rinv + NBN;
    f16* wc1H = (f16*)(adjrs + NBN);
    f16* wc1L = wc1H + (size_t)128 * KP;
    f16* w2tH = wc1L + (size_t)128 * KP;
    f16* w2tL = w2tH + 128 * 128;
    float* bc1p = (float*)(w2tL + 128 * 128);
    int* kidx = (int*)(bc1p + 128);

    k_prep2<<<NBN / 4, 256, 0, stream>>>(context, lens, glw, maskA, invn, F16);
    k_prepw<<<KP + 1, 128, 0, stream>>>(w_enc, w1, b_enc, w2, wc1H, wc1L, bc1p, w2tH, w2tL);
    k_sim_mfma<<<dim3(8, 8, cB), 256, 0, stream>>>(F16, maskA, invn, G0, RAh);
    k_topk<<<NBN / 4, 256, 0, stream>>>(G0, maskA, kidx, rinv);
    k_adj2<<<NBN, 256, 0, stream>>>(RAh, rinv, kidx, adjH, adjL, adjrs);

    // E1 = X @ (w_enc@w1), transposed split output [b][128][512]
    k_gemm_sp<0, false, true, true><<<NBN / 64, 256, 0, stream>>>(
        XH, XL, wc1H, wc1L, 0, KP, nullptr, nullptr, nullptr, nullptr, E1tH, E1tL);
    // h = relu(adj @ E1 + adjrs*bc1p + b1), split output [24576][128]
    k_gemm_sp<2, true, true, false><<<NBN / 64, 256, 0, stream>>>(
        adjH, adjL, E1tH, E1tL, 65536, cN, b1, bc1p, adjrs, nullptr, hH, hL);
    // H2 = h @ w2, transposed split output [b][128][512]
    k_gemm_sp<0, false, true, true><<<NBN / 64, 256, 0, stream>>>(
        hH, hL, w2tH, w2tL, 0, cHID, nullptr, nullptr, nullptr, nullptr, H2tH, H2tL);
    // nv = adj @ H2 + b2, fp32 output [24576][128]
    k_gemm_sp<1, false, false, false><<<NBN / 64, 256, 0, stream>>>(
        adjH, adjL, H2tH, H2tL, 65536, cN, b2, nullptr, nullptr, nv, nullptr, nullptr);

    k_final<<<cB, 512, 0, stream>>>(nv, ments, lw, lb, out);
}

// Round 4
// 372.813 us; speedup vs baseline: 3.5337x; 1.1156x over previous
//
#include <hip/hip_runtime.h>
#include <math.h>

// Problem constants
constexpr int cB = 48, cN = 512, cIN = 400;
constexpr int cENC = 256, cHID = 128, cOUT = 128, cNREL = 53;
constexpr int cKNN = 10;
constexpr float cVSN = 1e-12f;
constexpr float cEPS = 0.3f;

constexpr int KP = 416;                        // cIN padded to multiple of 32
constexpr size_t ARRSZ = (size_t)cB * cN * KP; // elems per f16 array (10,223,616)
constexpr int NBN = cB * cN;                   // 24576 rows
constexpr size_t NADJ = (size_t)cB * cN * cN;  // 12,582,912
constexpr size_t NE1 = (size_t)NBN * 128;      // 3,145,728

typedef _Float16 f16;
typedef _Float16 f16x8 __attribute__((ext_vector_type(8)));
typedef float f32x4 __attribute__((ext_vector_type(4)));

__device__ inline unsigned long long shfl_xor_u64(unsigned long long v, int off) {
    int lo = __shfl_xor((int)(unsigned)(v & 0xffffffffull), off, 64);
    int hi = __shfl_xor((int)(unsigned)(v >> 32), off, 64);
    return ((unsigned long long)(unsigned)hi << 32) | (unsigned)lo;
}

__device__ inline void gload16(const void* g, void* l) {
    __builtin_amdgcn_global_load_lds(
        (const __attribute__((address_space(1))) unsigned int*)g,
        (__attribute__((address_space(3))) unsigned int*)l, 16, 0, 0);
}

#define MFMA16(a, b, c) __builtin_amdgcn_mfma_f32_16x16x32_f16((a), (b), (c), 0, 0, 0)

// ---------------- K0: mask + inv-norms + XH/XL split arrays ----------------
__global__ void k_prep2(const float* __restrict__ X, const int* __restrict__ lens,
                        const float* __restrict__ glw,
                        float* __restrict__ mask, float* __restrict__ invn,
                        f16* __restrict__ XH, f16* __restrict__ XL)
{
    int row = blockIdx.x * 4 + (threadIdx.x >> 6);
    int lane = threadIdx.x & 63;
    int b = row >> 9, n = row & (cN - 1);
    const float* x = X + (long long)row * cIN;
    float s0 = 0.f, s1 = 0.f, s2 = 0.f, s3 = 0.f;
    if (lane < 52) {
        int k = lane * 8;
        f16x8 vh, vl;
        #pragma unroll
        for (int e = 0; e < 8; ++e) {
            int d = k + e;
            float xv = (d < cIN) ? x[d] : 0.f;
            float g0 = (d < cIN) ? glw[0 * cIN + d] : 0.f;
            float g1 = (d < cIN) ? glw[1 * cIN + d] : 0.f;
            float g2 = (d < cIN) ? glw[2 * cIN + d] : 0.f;
            float g3 = (d < cIN) ? glw[3 * cIN + d] : 0.f;
            float x2 = xv * xv;
            s0 += x2 * g0 * g0; s1 += x2 * g1 * g1;
            s2 += x2 * g2 * g2; s3 += x2 * g3 * g3;
            f16 hh = (f16)xv;
            vh[e] = hh; vl[e] = (f16)(xv - (float)hh);
        }
        size_t base = (size_t)row * KP + k;
        *(f16x8*)(XH + base) = vh;
        *(f16x8*)(XL + base) = vl;
    }
    #pragma unroll
    for (int off = 32; off; off >>= 1) {
        s0 += __shfl_xor(s0, off, 64);
        s1 += __shfl_xor(s1, off, 64);
        s2 += __shfl_xor(s2, off, 64);
        s3 += __shfl_xor(s3, off, 64);
    }
    if (lane == 0) {
        mask[row] = (n < lens[b]) ? 1.0f : 0.0f;
        invn[0 * NBN + row] = 1.0f / fmaxf(sqrtf(s0), cVSN);
        invn[1 * NBN + row] = 1.0f / fmaxf(sqrtf(s1), cVSN);
        invn[2 * NBN + row] = 1.0f / fmaxf(sqrtf(s2), cVSN);
        invn[3 * NBN + row] = 1.0f / fmaxf(sqrtf(s3), cVSN);
    }
}

// ---------------- K0b: fused weight prep ----------------
__global__ void k_prepw(const float* __restrict__ w_enc, const float* __restrict__ w1,
                        const float* __restrict__ b_enc, const float* __restrict__ w2,
                        f16* __restrict__ wc1H, f16* __restrict__ wc1L,
                        float* __restrict__ bc1p,
                        f16* __restrict__ w2tH, f16* __restrict__ w2tL)
{
    int d = blockIdx.x;      // 0..416
    int o = threadIdx.x;     // 0..127
    if (d < KP) {
        float acc = 0.f;
        if (d < cIN)
            for (int e = 0; e < cENC; ++e) acc += w_enc[(size_t)d * cENC + e] * w1[(size_t)e * cHID + o];
        f16 h = (f16)acc;
        wc1H[(size_t)o * KP + d] = h;
        wc1L[(size_t)o * KP + d] = (f16)(acc - (float)h);
        if (d < cHID) {
            float v = w2[(size_t)d * cOUT + o];
            f16 h2 = (f16)v;
            w2tH[(size_t)o * cHID + d] = h2;
            w2tL[(size_t)o * cHID + d] = (f16)(v - (float)h2);
        }
    } else {
        float acc = 0.f;
        for (int e = 0; e < cENC; ++e) acc += b_enc[e] * w1[(size_t)e * cHID + o];
        bc1p[o] = acc;
    }
}

// ---------------- K1: MFMA similarity, double-buffered, w2 on the fly ----------------
__global__ __launch_bounds__(256, 3) void k_sim_mfma(
    const f16* __restrict__ XH, const f16* __restrict__ XL,
    const float* __restrict__ glw,
    const float* __restrict__ maskA, const float* __restrict__ invn,
    float* __restrict__ G0, f16* __restrict__ RAh)
{
    // bijective XCD swizzle: all 64 blocks of a batch on one XCD
    int L = blockIdx.x + (blockIdx.y << 3) + (blockIdx.z << 6);
    int xcd = L & 7, j0 = L >> 3;
    int work = xcd * 384 + j0;
    const int b = work >> 6;
    int rem = work & 63;
    const int n0 = (rem >> 3) * 64, m0 = (rem & 7) * 64;

    const int t = threadIdx.x;
    const int w = t >> 6, lane = t & 63;
    const int wr = w >> 1, wc = w & 1;
    const int lr = lane & 15, lc = lane >> 4;

    __shared__ f16 lds[2][8192];   // 2 bufs x 4 tiles x [64 rows][4 slots][8 f16]
    __shared__ f16 w2l[4][KP];

    for (int i = t; i < 4 * KP; i += 256) {
        int p = i / KP, d = i - p * KP;
        float g = (d < cIN) ? glw[p * cIN + d] : 0.f;
        w2l[p][d] = (f16)(g * g);
    }

    f32x4 accG[2][2], accP[4][2][2];
    #pragma unroll
    for (int i = 0; i < 2; ++i)
        #pragma unroll
        for (int jj = 0; jj < 2; ++jj) {
            accG[i][jj] = (f32x4)0.f;
            #pragma unroll
            for (int p = 0; p < 4; ++p) accP[p][i][jj] = (f32x4)0.f;
        }

    const size_t rowBaseB = (size_t)b * cN;
    const int srow = lane >> 2, sslot = lane & 3;
    const f16* arrw = (w & 1) ? XL : XH;
    const int rb = (w < 2) ? n0 : m0;

#define SIM_STAGE(buf, pan) do { \
    const int kk0_ = (pan) * 32; \
    _Pragma("unroll") \
    for (int q = 0; q < 4; ++q) { \
        int row_ = q * 16 + srow; \
        int kcg_ = sslot ^ (row_ & 3) ^ ((row_ >> 2) & 3); \
        const f16* g_ = arrw + (rowBaseB + rb + row_) * (size_t)KP + kk0_ + kcg_ * 8; \
        gload16(g_, (void*)&lds[buf][(w * 4 + q) * 512]); \
    } \
} while (0)

    SIM_STAGE(0, 0);
    __syncthreads();

    for (int pan = 0; pan < KP / 32; ++pan) {
        int cur = pan & 1;
        if (pan + 1 < KP / 32) SIM_STAGE(cur ^ 1, pan + 1);
        const f16x8* L8 = (const f16x8*)lds[cur];
        const int kk0 = pan * 32;
        f16x8 aH[2], aL[2], bH[2], bL[2], wp[4];
        #pragma unroll
        for (int i = 0; i < 2; ++i) {
            int r = wr * 32 + i * 16 + lr;
            int cell = r * 4 + (lc ^ (r & 3) ^ ((r >> 2) & 3));
            aH[i] = L8[cell];
            aL[i] = L8[256 + cell];
        }
        #pragma unroll
        for (int jj = 0; jj < 2; ++jj) {
            int r = wc * 32 + jj * 16 + lr;
            int cell = r * 4 + (lc ^ (r & 3) ^ ((r >> 2) & 3));
            bH[jj] = L8[512 + cell];
            bL[jj] = L8[768 + cell];
        }
        #pragma unroll
        for (int p = 0; p < 4; ++p) wp[p] = *(const f16x8*)&w2l[p][kk0 + lc * 8];

        __builtin_amdgcn_s_setprio(1);
        #pragma unroll
        for (int i = 0; i < 2; ++i)
            #pragma unroll
            for (int jj = 0; jj < 2; ++jj) {
                accG[i][jj] = MFMA16(aH[i], bH[jj], accG[i][jj]);
                accG[i][jj] = MFMA16(aH[i], bL[jj], accG[i][jj]);
                accG[i][jj] = MFMA16(aL[i], bH[jj], accG[i][jj]);
            }
        #pragma unroll
        for (int p = 0; p < 4; ++p)
            #pragma unroll
            for (int i = 0; i < 2; ++i) {
                f16x8 ap = aH[i] * wp[p];
                #pragma unroll
                for (int jj = 0; jj < 2; ++jj)
                    accP[p][i][jj] = MFMA16(ap, bH[jj], accP[p][i][jj]);
            }
        __builtin_amdgcn_s_setprio(0);
        __syncthreads();
    }
#undef SIM_STAGE

    // epilogue: mask, cosine-normalize, sparsify; NT stores
    #pragma unroll
    for (int i = 0; i < 2; ++i) {
        #pragma unroll
        for (int jj = 0; jj < 2; ++jj) {
            int m = m0 + wc * 32 + jj * 16 + lr;
            size_t rowm = rowBaseB + m;
            float mskm = maskA[rowm];
            float im0 = invn[0 * NBN + rowm], im1 = invn[1 * NBN + rowm];
            float im2 = invn[2 * NBN + rowm], im3 = invn[3 * NBN + rowm];
            #pragma unroll
            for (int v = 0; v < 4; ++v) {
                int n = n0 + wr * 32 + i * 16 + lc * 4 + v;
                size_t rown = rowBaseB + n;
                float mk = maskA[rown] * mskm;
                float g = accG[i][jj][v] * mk;
                float s = 0.25f * (accP[0][i][jj][v] * invn[0 * NBN + rown] * im0
                                 + accP[1][i][jj][v] * invn[1 * NBN + rown] * im1
                                 + accP[2][i][jj][v] * invn[2 * NBN + rown] * im2
                                 + accP[3][i][jj][v] * invn[3 * NBN + rown] * im3) * mk;
                float rv = (s > cEPS) ? s : 0.f;
                __builtin_nontemporal_store(g, &G0[rown * cN + m]);
                __builtin_nontemporal_store((f16)rv, &RAh[rown * cN + m]);
            }
        }
    }
}

// ---------------- K2: per-row top-10 (value desc, index asc) ----------------
__global__ void k_topk(const float* __restrict__ G0, const float* __restrict__ mask,
                       int* __restrict__ kidx, float* __restrict__ rinv)
{
    int row = blockIdx.x * 4 + (threadIdx.x >> 6);
    int lane = threadIdx.x & 63;
    int b = row >> 9, n = row & (cN - 1);
    const float* g = G0 + (long long)row * cN;
    unsigned long long key[8];
    #pragma unroll
    for (int k = 0; k < 8; ++k) {
        int col = lane + 64 * k;
        float v = __builtin_nontemporal_load(&g[col]);
        unsigned u = __float_as_uint(v);
        u ^= (unsigned)(((int)u >> 31)) | 0x80000000u;
        key[k] = ((unsigned long long)u << 32) | (unsigned)(cN - 1 - col);
    }
    float cnt = 0.f;
    long long mbase = (long long)b * cN;
    for (int r = 0; r < cKNN; ++r) {
        unsigned long long best = 0ull;
        #pragma unroll
        for (int k = 0; k < 8; ++k) best = (key[k] > best) ? key[k] : best;
        #pragma unroll
        for (int off = 32; off; off >>= 1) {
            unsigned long long o = shfl_xor_u64(best, off);
            if (o > best) best = o;
        }
        int col = (cN - 1) - (int)(best & 0xffffffffull);
        #pragma unroll
        for (int k = 0; k < 8; ++k) if (key[k] == best) key[k] = 0ull;
        if (lane == 0) {
            kidx[row * cKNN + r] = col;
            cnt += mask[mbase + col];
        }
    }
    if (lane == 0) {
        float mk = mask[mbase + n];
        rinv[row] = (mk > 0.f) ? rsqrtf(fmaxf(cnt, cVSN)) : 0.f;
    }
}

// ---------------- K3: adjacency assembly (fused rowsum, split-f16 out, adjrs) -------
__global__ void k_adj2(const f16* __restrict__ RAh, const float* __restrict__ rinv,
                       const int* __restrict__ kidx,
                       f16* __restrict__ adjH, f16* __restrict__ adjL,
                       float* __restrict__ adjrs)
{
    int row = blockIdx.x;
    int t = threadIdx.x;  // 256
    int w = t >> 6, lane = t & 63;
    __shared__ int sidx[cKNN];
    __shared__ float srv[cKNN];
    __shared__ float red[4];
    long long bbase = (long long)(row & ~(cN - 1));
    if (t < cKNN) {
        int c = kidx[row * cKNN + t];
        sidx[t] = c;
        srv[t] = rinv[bbase + c];
    }
    long long base = (long long)row * cN;
    float ra0 = (float)__builtin_nontemporal_load(&RAh[base + t]);
    float ra1 = (float)__builtin_nontemporal_load(&RAh[base + t + 256]);
    float s = ra0 + ra1;
    #pragma unroll
    for (int off = 32; off; off >>= 1) s += __shfl_xor(s, off, 64);
    if (lane == 0) red[w] = s;
    __syncthreads();
    float rsum = red[0] + red[1] + red[2] + red[3];
    float inv_rs = 1.0f / fmaxf(rsum, cVSN);
    float rn = rinv[row];
    float osum = 0.f;
    #pragma unroll
    for (int mi = 0; mi < 2; ++mi) {
        int m = t + mi * 256;
        float ra = mi ? ra1 : ra0;
        float v = 0.2f * ra * inv_rs;
        #pragma unroll
        for (int k = 0; k < cKNN; ++k)
            if (m == sidx[k]) v += 0.8f * rn * srv[k];
        f16 hh = (f16)v;
        adjH[base + m] = hh;
        adjL[base + m] = (f16)(v - (float)hh);
        osum += v;
    }
    #pragma unroll
    for (int off = 32; off; off >>= 1) osum += __shfl_xor(osum, off, 64);
    __syncthreads();
    if (lane == 0) red[w] = osum;
    __syncthreads();
    if (t == 0) adjrs[row] = red[0] + red[1] + red[2] + red[3];
}

// ---------------- Unified split-f16 MFMA GEMM, BM=64 BN=64, double-buffered -------
// BIAS: 0 none, 1 +biasv[col], 2 +adjrs[row]*bc1p[col]+biasv[col]
template<int BIAS, bool RELU, bool OSPLIT, bool OTRANS>
__global__ __launch_bounds__(256, 3) void k_gemm_sp(
    const f16* __restrict__ AH, const f16* __restrict__ AL,
    const f16* __restrict__ BHp, const f16* __restrict__ BLp,
    long long bStrideB, int K,
    const float* __restrict__ biasv, const float* __restrict__ bc1p,
    const float* __restrict__ adjrs,
    float* __restrict__ Cf, f16* __restrict__ CH, f16* __restrict__ CL)
{
    // bijective XCD swizzle over 768 blocks; pair (bx, both bn) contiguous
    int L = blockIdx.x + blockIdx.y * gridDim.x;
    int work = (L & 7) * 96 + (L >> 3);
    const int R0 = (work >> 1) * 64;
    const int bn0 = (work & 1) * 64;
    const int bidx = R0 >> 9;
    const int t = threadIdx.x, w = t >> 6, lane = t & 63;
    const int wr = w >> 1, wc = w & 1, lr = lane & 15, lc = lane >> 4;
    __shared__ f16 lds[2][8192];   // 2 x 16KB: AH 0..255, AL 256.., BH 512.., BL 768..
    const f16* Bh = BHp + (size_t)bidx * bStrideB + (size_t)bn0 * K;
    const f16* Bl = BLp + (size_t)bidx * bStrideB + (size_t)bn0 * K;

    f32x4 acc[2][2];
    #pragma unroll
    for (int i = 0; i < 2; ++i)
        #pragma unroll
        for (int jj = 0; jj < 2; ++jj) acc[i][jj] = (f32x4)0.f;

#define GEMM_STAGE(buf, p_) do { \
    const int k0_ = (p_) * 32; \
    _Pragma("unroll") \
    for (int q = 0; q < 4; ++q) { \
        int e_ = (w * 4 + q) * 64 + lane; \
        int ci_ = e_ & 255; \
        int row_ = ci_ >> 2, slot_ = ci_ & 3; \
        int kc_ = slot_ ^ (row_ & 3) ^ ((row_ >> 2) & 3); \
        const f16* src_; \
        if (e_ < 512) src_ = ((e_ < 256) ? AH : AL) + (size_t)(R0 + row_) * K + k0_ + kc_ * 8; \
        else          src_ = ((e_ < 768) ? Bh : Bl) + (size_t)row_ * K + k0_ + kc_ * 8; \
        gload16(src_, (void*)&lds[buf][(w * 4 + q) * 512]); \
    } \
} while (0)

    const int npan = K >> 5;
    GEMM_STAGE(0, 0);
    __syncthreads();
    for (int p = 0; p < npan; ++p) {
        int cur = p & 1;
        if (p + 1 < npan) GEMM_STAGE(cur ^ 1, p + 1);
        const f16x8* L8 = (const f16x8*)lds[cur];
        f16x8 aH[2], aL[2], bH[2], bL[2];
        #pragma unroll
        for (int i = 0; i < 2; ++i) {
            int r = wr * 32 + i * 16 + lr;
            int cell = r * 4 + (lc ^ (r & 3) ^ ((r >> 2) & 3));
            aH[i] = L8[cell];
            aL[i] = L8[256 + cell];
        }
        #pragma unroll
        for (int jj = 0; jj < 2; ++jj) {
            int r = wc * 32 + jj * 16 + lr;
            int cell = r * 4 + (lc ^ (r & 3) ^ ((r >> 2) & 3));
            bH[jj] = L8[512 + cell];
            bL[jj] = L8[768 + cell];
        }
        __builtin_amdgcn_s_setprio(1);
        #pragma unroll
        for (int i = 0; i < 2; ++i)
            #pragma unroll
            for (int jj = 0; jj < 2; ++jj) {
                acc[i][jj] = MFMA16(aH[i], bH[jj], acc[i][jj]);
                acc[i][jj] = MFMA16(aH[i], bL[jj], acc[i][jj]);
                acc[i][jj] = MFMA16(aL[i], bH[jj], acc[i][jj]);
            }
        __builtin_amdgcn_s_setprio(0);
        __syncthreads();
    }
#undef GEMM_STAGE

    #pragma unroll
    for (int i = 0; i < 2; ++i)
        #pragma unroll
        for (int jj = 0; jj < 2; ++jj) {
            int col = bn0 + wc * 32 + jj * 16 + lr;
            #pragma unroll
            for (int v = 0; v < 4; ++v) {
                int r = R0 + wr * 32 + i * 16 + lc * 4 + v;
                float val = acc[i][jj][v];
                if (BIAS == 1) val += biasv[col];
                if (BIAS == 2) val += adjrs[r] * bc1p[col] + biasv[col];
                if (RELU) val = fmaxf(val, 0.f);
                if (!OSPLIT) {
                    Cf[(size_t)r * 128 + col] = val;
                } else {
                    f16 hh = (f16)val;
                    f16 ll = (f16)(val - (float)hh);
                    size_t addr = OTRANS
                        ? ((size_t)(r >> 9) * 65536 + (size_t)col * 512 + (r & 511))
                        : ((size_t)r * 128 + col);
                    CH[addr] = hh;
                    CL[addr] = ll;
                }
            }
        }
}

// ---------------- K5: maxpool + mention merge + final linear ----------------
__global__ void k_final(const float* __restrict__ nv, const int* __restrict__ mentions,
                        const float* __restrict__ lw, const float* __restrict__ lb,
                        float* __restrict__ out)
{
    int b = blockIdx.x;
    int t = threadIdx.x;            // 512
    int d = t & 127, g = t >> 7;
    __shared__ float smx[4][128], sa1[4][128], sa2[4][128];
    int s1 = mentions[b * 4 + 0], e1 = mentions[b * 4 + 1];
    int s2 = mentions[b * 4 + 2], e2 = mentions[b * 4 + 3];
    const float* p = nv + (long long)b * cN * cOUT;
    float mx = -INFINITY, a1 = 0.f, a2 = 0.f;
    for (int n = g * 128; n < (g + 1) * 128; ++n) {
        float v = p[n * cOUT + d];
        mx = fmaxf(mx, v);
        if (n >= s1 && n <= e1) a1 += v;
        if (n >= s2 && n <= e2) a2 += v;
    }
    smx[g][d] = mx; sa1[g][d] = a1; sa2[g][d] = a2;
    __syncthreads();
    if (t < 128) {
        float m2 = fmaxf(fmaxf(smx[0][t], smx[1][t]), fmaxf(smx[2][t], smx[3][t]));
        float b1s = sa1[0][t] + sa1[1][t] + sa1[2][t] + sa1[3][t];
        float b2s = sa2[0][t] + sa2[1][t] + sa2[2][t] + sa2[3][t];
        smx[0][t] = m2 + b1s / (float)(e1 - s1 + 1) + b2s / (float)(e2 - s2 + 1);
    }
    __syncthreads();
    if (t < cNREL) {
        float s = lb[t];
        for (int dd = 0; dd < cOUT; ++dd) s += smx[0][dd] * lw[dd * cNREL + t];
        out[b * cNREL + t] = s;
    }
}

extern "C" void kernel_launch(void* const* d_in, const int* in_sizes, int n_in,
                              void* d_out, int out_size, void* d_ws, size_t ws_size,
                              hipStream_t stream)
{
    const float* context = (const float*)d_in[0];
    const int*   lens    = (const int*)d_in[1];
    const int*   ments   = (const int*)d_in[2];
    const float* w_enc   = (const float*)d_in[3];
    const float* b_enc   = (const float*)d_in[4];
    const float* glw     = (const float*)d_in[5];
    const float* w1      = (const float*)d_in[6];
    const float* b1      = (const float*)d_in[7];
    const float* w2      = (const float*)d_in[8];
    const float* b2      = (const float*)d_in[9];
    const float* lw      = (const float*)d_in[10];
    const float* lb      = (const float*)d_in[11];
    float* out = (float*)d_out;

    // ---- workspace layout ----
    f16* XH   = (f16*)d_ws;
    f16* XL   = XH + ARRSZ;
    f16* adjH = XL + ARRSZ;
    f16* adjL = adjH + NADJ;
    f16* E1tH = adjL + NADJ;
    f16* E1tL = E1tH + NE1;
    f16* hH   = E1tL + NE1;
    f16* hL   = hH + NE1;
    float* G0 = (float*)(hL + NE1);             // NADJ floats; reused for H2t + nv
    f16* H2tH = (f16*)G0;
    f16* H2tL = H2tH + NE1;
    float* nv = G0 + NE1;
    f16* RAh  = (f16*)(G0 + NADJ);              // NADJ f16
    float* invn  = (float*)(RAh + NADJ);        // 4*NBN
    float* maskA = invn + 4 * NBN;
    float* rinv  = maskA + NBN;
    float* adjrs = rinv + NBN;
    f16* wc1H = (f16*)(adjrs + NBN);
    f16* wc1L = wc1H + (size_t)128 * KP;
    f16* w2tH = wc1L + (size_t)128 * KP;
    f16* w2tL = w2tH + 128 * 128;
    float* bc1p = (float*)(w2tL + 128 * 128);
    int* kidx = (int*)(bc1p + 128);

    k_prep2<<<NBN / 4, 256, 0, stream>>>(context, lens, glw, maskA, invn, XH, XL);
    k_prepw<<<KP + 1, 128, 0, stream>>>(w_enc, w1, b_enc, w2, wc1H, wc1L, bc1p, w2tH, w2tL);
    k_sim_mfma<<<dim3(8, 8, cB), 256, 0, stream>>>(XH, XL, glw, maskA, invn, G0, RAh);
    k_topk<<<NBN / 4, 256, 0, stream>>>(G0, maskA, kidx, rinv);
    k_adj2<<<NBN, 256, 0, stream>>>(RAh, rinv, kidx, adjH, adjL, adjrs);

    // E1 = X @ (w_enc@w1), transposed split output [b][128][512]
    k_gemm_sp<0, false, true, true><<<dim3(NBN / 64, 2), 256, 0, stream>>>(
        XH, XL, wc1H, wc1L, 0, KP, nullptr, nullptr, nullptr, nullptr, E1tH, E1tL);
    // h = relu(adj @ E1 + adjrs*bc1p + b1), split output [24576][128]
    k_gemm_sp<2, true, true, false><<<dim3(NBN / 64, 2), 256, 0, stream>>>(
        adjH, adjL, E1tH, E1tL, 65536, cN, b1, bc1p, adjrs, nullptr, hH, hL);
    // H2 = h @ w2, transposed split output [b][128][512]
    k_gemm_sp<0, false, true, true><<<dim3(NBN / 64, 2), 256, 0, stream>>>(
        hH, hL, w2tH, w2tL, 0, cHID, nullptr, nullptr, nullptr, nullptr, H2tH, H2tL);
    // nv = adj @ H2 + b2, fp32 output [24576][128]
    k_gemm_sp<1, false, false, false><<<dim3(NBN / 64, 2), 256, 0, stream>>>(
        adjH, adjL, H2tH, H2tL, 65536, cN, b2, nullptr, nullptr, nv, nullptr, nullptr);

    k_final<<<cB, 512, 0, stream>>>(nv, ments, lw, lb, out);
}

// Round 5
// 296.337 us; speedup vs baseline: 4.4457x; 1.2581x over previous
//
#include <hip/hip_runtime.h>
#include <math.h>

// Problem constants
constexpr int cB = 48, cN = 512, cIN = 400;
constexpr int cENC = 256, cHID = 128, cOUT = 128, cNREL = 53;
constexpr int cKNN = 10;
constexpr float cVSN = 1e-12f;
constexpr float cEPS = 0.3f;

constexpr int KP = 416;                        // cIN padded to multiple of 32
constexpr size_t ARRSZ = (size_t)cB * cN * KP; // elems per f16 array
constexpr int NBN = cB * cN;                   // 24576 rows
constexpr size_t NADJ = (size_t)cB * cN * cN;  // 12,582,912
constexpr size_t NE1 = (size_t)NBN * 128;      // 3,145,728

typedef _Float16 f16;
typedef _Float16 f16x8 __attribute__((ext_vector_type(8)));
typedef float f32x4 __attribute__((ext_vector_type(4)));

__device__ inline unsigned long long shfl_xor_u64(unsigned long long v, int off) {
    int lo = __shfl_xor((int)(unsigned)(v & 0xffffffffull), off, 64);
    int hi = __shfl_xor((int)(unsigned)(v >> 32), off, 64);
    return ((unsigned long long)(unsigned)hi << 32) | (unsigned)lo;
}

__device__ inline void gload16(const void* g, void* l) {
    __builtin_amdgcn_global_load_lds(
        (const __attribute__((address_space(1))) unsigned int*)g,
        (__attribute__((address_space(3))) unsigned int*)l, 16, 0, 0);
}

#define MFMA16(a, b, c) __builtin_amdgcn_mfma_f32_16x16x32_f16((a), (b), (c), 0, 0, 0)

// ---------------- K0: mask + inv-norms + XH/XL split arrays ----------------
__global__ void k_prep2(const float* __restrict__ X, const int* __restrict__ lens,
                        const float* __restrict__ glw,
                        float* __restrict__ mask, float* __restrict__ invn,
                        f16* __restrict__ XH, f16* __restrict__ XL)
{
    int row = blockIdx.x * 4 + (threadIdx.x >> 6);
    int lane = threadIdx.x & 63;
    int b = row >> 9, n = row & (cN - 1);
    const float* x = X + (long long)row * cIN;
    float s0 = 0.f, s1 = 0.f, s2 = 0.f, s3 = 0.f;
    if (lane < 52) {
        int k = lane * 8;
        f16x8 vh, vl;
        #pragma unroll
        for (int e = 0; e < 8; ++e) {
            int d = k + e;
            float xv = (d < cIN) ? x[d] : 0.f;
            float g0 = (d < cIN) ? glw[0 * cIN + d] : 0.f;
            float g1 = (d < cIN) ? glw[1 * cIN + d] : 0.f;
            float g2 = (d < cIN) ? glw[2 * cIN + d] : 0.f;
            float g3 = (d < cIN) ? glw[3 * cIN + d] : 0.f;
            float x2 = xv * xv;
            s0 += x2 * g0 * g0; s1 += x2 * g1 * g1;
            s2 += x2 * g2 * g2; s3 += x2 * g3 * g3;
            f16 hh = (f16)xv;
            vh[e] = hh; vl[e] = (f16)(xv - (float)hh);
        }
        size_t base = (size_t)row * KP + k;
        *(f16x8*)(XH + base) = vh;
        *(f16x8*)(XL + base) = vl;
    }
    #pragma unroll
    for (int off = 32; off; off >>= 1) {
        s0 += __shfl_xor(s0, off, 64);
        s1 += __shfl_xor(s1, off, 64);
        s2 += __shfl_xor(s2, off, 64);
        s3 += __shfl_xor(s3, off, 64);
    }
    if (lane == 0) {
        mask[row] = (n < lens[b]) ? 1.0f : 0.0f;
        invn[0 * NBN + row] = 1.0f / fmaxf(sqrtf(s0), cVSN);
        invn[1 * NBN + row] = 1.0f / fmaxf(sqrtf(s1), cVSN);
        invn[2 * NBN + row] = 1.0f / fmaxf(sqrtf(s2), cVSN);
        invn[3 * NBN + row] = 1.0f / fmaxf(sqrtf(s3), cVSN);
    }
}

// ---------------- K0b: fused weight prep (single f16 now) ----------------
__global__ void k_prepw(const float* __restrict__ w_enc, const float* __restrict__ w1,
                        const float* __restrict__ b_enc, const float* __restrict__ w2,
                        f16* __restrict__ wc1H, float* __restrict__ bc1p,
                        f16* __restrict__ w2tH)
{
    int d = blockIdx.x;      // 0..416
    int o = threadIdx.x;     // 0..127
    if (d < KP) {
        float acc = 0.f;
        if (d < cIN)
            for (int e = 0; e < cENC; ++e) acc += w_enc[(size_t)d * cENC + e] * w1[(size_t)e * cHID + o];
        wc1H[(size_t)o * KP + d] = (f16)acc;
        if (d < cHID)
            w2tH[(size_t)o * cHID + d] = (f16)w2[(size_t)d * cOUT + o];
    } else {
        float acc = 0.f;
        for (int e = 0; e < cENC; ++e) acc += b_enc[e] * w1[(size_t)e * cHID + o];
        bc1p[o] = acc;
    }
}

// ---------------- K1: MFMA similarity, double-buffered, w2 on the fly ----------------
__global__ __launch_bounds__(256, 3) void k_sim_mfma(
    const f16* __restrict__ XH, const f16* __restrict__ XL,
    const float* __restrict__ glw,
    const float* __restrict__ maskA, const float* __restrict__ invn,
    float* __restrict__ G0, f16* __restrict__ RAh)
{
    // bijective XCD swizzle: all 64 blocks of a batch on one XCD
    int L = blockIdx.x + (blockIdx.y << 3) + (blockIdx.z << 6);
    int xcd = L & 7, j0 = L >> 3;
    int work = xcd * 384 + j0;
    const int b = work >> 6;
    int rem = work & 63;
    const int n0 = (rem >> 3) * 64, m0 = (rem & 7) * 64;

    const int t = threadIdx.x;
    const int w = t >> 6, lane = t & 63;
    const int wr = w >> 1, wc = w & 1;
    const int lr = lane & 15, lc = lane >> 4;

    __shared__ f16 lds[2][8192];   // 2 bufs x 4 tiles x [64 rows][4 slots][8 f16]
    __shared__ f16 w2l[4][KP];

    for (int i = t; i < 4 * KP; i += 256) {
        int p = i / KP, d = i - p * KP;
        float g = (d < cIN) ? glw[p * cIN + d] : 0.f;
        w2l[p][d] = (f16)(g * g);
    }

    f32x4 accG[2][2], accP[4][2][2];
    #pragma unroll
    for (int i = 0; i < 2; ++i)
        #pragma unroll
        for (int jj = 0; jj < 2; ++jj) {
            accG[i][jj] = (f32x4)0.f;
            #pragma unroll
            for (int p = 0; p < 4; ++p) accP[p][i][jj] = (f32x4)0.f;
        }

    const size_t rowBaseB = (size_t)b * cN;
    const int srow = lane >> 2, sslot = lane & 3;
    const f16* arrw = (w & 1) ? XL : XH;
    const int rb = (w < 2) ? n0 : m0;

#define SIM_STAGE(buf, pan) do { \
    const int kk0_ = (pan) * 32; \
    _Pragma("unroll") \
    for (int q = 0; q < 4; ++q) { \
        int row_ = q * 16 + srow; \
        int kcg_ = sslot ^ (row_ & 3) ^ ((row_ >> 2) & 3); \
        const f16* g_ = arrw + (rowBaseB + rb + row_) * (size_t)KP + kk0_ + kcg_ * 8; \
        gload16(g_, (void*)&lds[buf][(w * 4 + q) * 512]); \
    } \
} while (0)

    SIM_STAGE(0, 0);
    __syncthreads();

    for (int pan = 0; pan < KP / 32; ++pan) {
        int cur = pan & 1;
        if (pan + 1 < KP / 32) SIM_STAGE(cur ^ 1, pan + 1);
        const f16x8* L8 = (const f16x8*)lds[cur];
        const int kk0 = pan * 32;
        f16x8 aH[2], aL[2], bH[2], bL[2], wp[4];
        #pragma unroll
        for (int i = 0; i < 2; ++i) {
            int r = wr * 32 + i * 16 + lr;
            int cell = r * 4 + (lc ^ (r & 3) ^ ((r >> 2) & 3));
            aH[i] = L8[cell];
            aL[i] = L8[256 + cell];
        }
        #pragma unroll
        for (int jj = 0; jj < 2; ++jj) {
            int r = wc * 32 + jj * 16 + lr;
            int cell = r * 4 + (lc ^ (r & 3) ^ ((r >> 2) & 3));
            bH[jj] = L8[512 + cell];
            bL[jj] = L8[768 + cell];
        }
        #pragma unroll
        for (int p = 0; p < 4; ++p) wp[p] = *(const f16x8*)&w2l[p][kk0 + lc * 8];

        __builtin_amdgcn_s_setprio(1);
        #pragma unroll
        for (int i = 0; i < 2; ++i)
            #pragma unroll
            for (int jj = 0; jj < 2; ++jj) {
                accG[i][jj] = MFMA16(aH[i], bH[jj], accG[i][jj]);
                accG[i][jj] = MFMA16(aH[i], bL[jj], accG[i][jj]);
                accG[i][jj] = MFMA16(aL[i], bH[jj], accG[i][jj]);
            }
        #pragma unroll
        for (int p = 0; p < 4; ++p)
            #pragma unroll
            for (int i = 0; i < 2; ++i) {
                f16x8 ap = aH[i] * wp[p];
                #pragma unroll
                for (int jj = 0; jj < 2; ++jj)
                    accP[p][i][jj] = MFMA16(ap, bH[jj], accP[p][i][jj]);
            }
        __builtin_amdgcn_s_setprio(0);
        __syncthreads();
    }
#undef SIM_STAGE

    // epilogue: mask, cosine-normalize, sparsify; G0 NT (streamed), RA normal (L2/L3)
    #pragma unroll
    for (int i = 0; i < 2; ++i) {
        #pragma unroll
        for (int jj = 0; jj < 2; ++jj) {
            int m = m0 + wc * 32 + jj * 16 + lr;
            size_t rowm = rowBaseB + m;
            float mskm = maskA[rowm];
            float im0 = invn[0 * NBN + rowm], im1 = invn[1 * NBN + rowm];
            float im2 = invn[2 * NBN + rowm], im3 = invn[3 * NBN + rowm];
            #pragma unroll
            for (int v = 0; v < 4; ++v) {
                int n = n0 + wr * 32 + i * 16 + lc * 4 + v;
                size_t rown = rowBaseB + n;
                float mk = maskA[rown] * mskm;
                float g = accG[i][jj][v] * mk;
                float s = 0.25f * (accP[0][i][jj][v] * invn[0 * NBN + rown] * im0
                                 + accP[1][i][jj][v] * invn[1 * NBN + rown] * im1
                                 + accP[2][i][jj][v] * invn[2 * NBN + rown] * im2
                                 + accP[3][i][jj][v] * invn[3 * NBN + rown] * im3) * mk;
                float rv = (s > cEPS) ? s : 0.f;
                __builtin_nontemporal_store(g, &G0[rown * cN + m]);
                RAh[rown * cN + m] = (f16)rv;
            }
        }
    }
}

// ---------------- K2: per-row top-10 (value desc, index asc) ----------------
__global__ void k_topk(const float* __restrict__ G0, const float* __restrict__ mask,
                       int* __restrict__ kidx, float* __restrict__ rinv)
{
    int row = blockIdx.x * 4 + (threadIdx.x >> 6);
    int lane = threadIdx.x & 63;
    int b = row >> 9, n = row & (cN - 1);
    const float* g = G0 + (long long)row * cN;
    unsigned long long key[8];
    #pragma unroll
    for (int k = 0; k < 8; ++k) {
        int col = lane + 64 * k;
        float v = __builtin_nontemporal_load(&g[col]);
        unsigned u = __float_as_uint(v);
        u ^= (unsigned)(((int)u >> 31)) | 0x80000000u;
        key[k] = ((unsigned long long)u << 32) | (unsigned)(cN - 1 - col);
    }
    float cnt = 0.f;
    long long mbase = (long long)b * cN;
    for (int r = 0; r < cKNN; ++r) {
        unsigned long long best = 0ull;
        #pragma unroll
        for (int k = 0; k < 8; ++k) best = (key[k] > best) ? key[k] : best;
        #pragma unroll
        for (int off = 32; off; off >>= 1) {
            unsigned long long o = shfl_xor_u64(best, off);
            if (o > best) best = o;
        }
        int col = (cN - 1) - (int)(best & 0xffffffffull);
        #pragma unroll
        for (int k = 0; k < 8; ++k) if (key[k] == best) key[k] = 0ull;
        if (lane == 0) {
            kidx[row * cKNN + r] = col;
            cnt += mask[mbase + col];
        }
    }
    if (lane == 0) {
        float mk = mask[mbase + n];
        rinv[row] = (mk > 0.f) ? rsqrtf(fmaxf(cnt, cVSN)) : 0.f;
    }
}

// ---------------- K3: adjacency assembly (fused rowsum, single f16 out, adjrs) -----
__global__ void k_adj2(const f16* __restrict__ RAh, const float* __restrict__ rinv,
                       const int* __restrict__ kidx,
                       f16* __restrict__ adjH, float* __restrict__ adjrs)
{
    int row = blockIdx.x;
    int t = threadIdx.x;  // 256
    int w = t >> 6, lane = t & 63;
    __shared__ int sidx[cKNN];
    __shared__ float srv[cKNN];
    __shared__ float red[4];
    long long bbase = (long long)(row & ~(cN - 1));
    if (t < cKNN) {
        int c = kidx[row * cKNN + t];
        sidx[t] = c;
        srv[t] = rinv[bbase + c];
    }
    long long base = (long long)row * cN;
    float ra0 = (float)RAh[base + t];
    float ra1 = (float)RAh[base + t + 256];
    float s = ra0 + ra1;
    #pragma unroll
    for (int off = 32; off; off >>= 1) s += __shfl_xor(s, off, 64);
    if (lane == 0) red[w] = s;
    __syncthreads();
    float rsum = red[0] + red[1] + red[2] + red[3];
    float inv_rs = 1.0f / fmaxf(rsum, cVSN);
    float rn = rinv[row];
    float osum = 0.f;
    #pragma unroll
    for (int mi = 0; mi < 2; ++mi) {
        int m = t + mi * 256;
        float ra = mi ? ra1 : ra0;
        float v = 0.2f * ra * inv_rs;
        #pragma unroll
        for (int k = 0; k < cKNN; ++k)
            if (m == sidx[k]) v += 0.8f * rn * srv[k];
        adjH[base + m] = (f16)v;
        osum += v;
    }
    #pragma unroll
    for (int off = 32; off; off >>= 1) osum += __shfl_xor(osum, off, 64);
    __syncthreads();
    if (lane == 0) red[w] = osum;
    __syncthreads();
    if (t == 0) adjrs[row] = red[0] + red[1] + red[2] + red[3];
}

// ---------------- Single-pass f16 MFMA GEMM, BM=64 BN=64 BK=32, double-buffered ----
// BIAS: 0 none, 1 +biasv[col] (OMODE2 only), 2 +adjrs[row]*bc1p[col]+biasv[col]
// OMODE: 0 f16 flat [r][128], 1 f16 transposed [b][col][512], 2 fused pool partials
template<int BIAS, bool RELU, int OMODE>
__global__ __launch_bounds__(256, 4) void k_gemm1(
    const f16* __restrict__ A, const f16* __restrict__ Bp,
    long long bStrideB, int K,
    const float* __restrict__ biasv, const float* __restrict__ bc1p,
    const float* __restrict__ adjrs, const int* __restrict__ ments,
    f16* __restrict__ CH, float* __restrict__ part)
{
    // bijective XCD swizzle over 768 blocks; (R0, both bn) consecutive per XCD
    int L = blockIdx.x + blockIdx.y * gridDim.x;
    int work = (L & 7) * 96 + (L >> 3);
    const int R0 = (work >> 1) * 64;
    const int bn0 = (work & 1) * 64;
    const int bidx = R0 >> 9;
    const int t = threadIdx.x, w = t >> 6, lane = t & 63;
    const int wr = w >> 1, wc = w & 1, lr = lane & 15, lc = lane >> 4;
    __shared__ f16 lds[2][4096];   // 2 x 8KB: A cells 0..255, B cells 256..511
    __shared__ float sred[2][3][64];
    const f16x8* L8A = (const f16x8*)lds[0];
    const f16* Bb = Bp + (size_t)bidx * bStrideB + (size_t)bn0 * K;

    f32x4 acc[2][2];
    #pragma unroll
    for (int i = 0; i < 2; ++i)
        #pragma unroll
        for (int jj = 0; jj < 2; ++jj) acc[i][jj] = (f32x4)0.f;

#define G1_STAGE(buf, p_) do { \
    const int k0_ = (p_) * 32; \
    _Pragma("unroll") \
    for (int q = 0; q < 2; ++q) { \
        int e_ = q * 256 + t; \
        int ci_ = e_ & 255; \
        int row_ = ci_ >> 2, slot_ = ci_ & 3; \
        int kc_ = slot_ ^ (row_ & 3) ^ ((row_ >> 2) & 3); \
        const f16* src_ = (e_ < 256) ? (A + (size_t)(R0 + row_) * K + k0_ + kc_ * 8) \
                                     : (Bb + (size_t)row_ * K + k0_ + kc_ * 8); \
        gload16(src_, (void*)&lds[buf][(size_t)e_ * 16 - ((e_ < 256) ? 0 : 4096) + ((e_ < 256) ? 0 : 4096)]); \
    } \
} while (0)

    // simpler correct staging (dst = e*8 f16 within buf)
#undef G1_STAGE
#define G1_STAGE(buf, p_) do { \
    const int k0_ = (p_) * 32; \
    _Pragma("unroll") \
    for (int q = 0; q < 2; ++q) { \
        int e_ = q * 256 + t; \
        int ci_ = e_ & 255; \
        int row_ = ci_ >> 2, slot_ = ci_ & 3; \
        int kc_ = slot_ ^ (row_ & 3) ^ ((row_ >> 2) & 3); \
        const f16* src_ = (e_ < 256) ? (A + (size_t)(R0 + row_) * K + k0_ + kc_ * 8) \
                                     : (Bb + (size_t)row_ * K + k0_ + kc_ * 8); \
        gload16(src_, (void*)&lds[buf][(size_t)e_ * 8]); \
    } \
} while (0)

    const int npan = K >> 5;
    G1_STAGE(0, 0);
    __syncthreads();
    for (int p = 0; p < npan; ++p) {
        int cur = p & 1;
        if (p + 1 < npan) G1_STAGE(cur ^ 1, p + 1);
        const f16x8* L8 = (const f16x8*)lds[cur];
        f16x8 af[2], bf[2];
        #pragma unroll
        for (int i = 0; i < 2; ++i) {
            int r = wr * 32 + i * 16 + lr;
            int cell = r * 4 + (lc ^ (r & 3) ^ ((r >> 2) & 3));
            af[i] = L8[cell];
        }
        #pragma unroll
        for (int jj = 0; jj < 2; ++jj) {
            int r = wc * 32 + jj * 16 + lr;
            int cell = r * 4 + (lc ^ (r & 3) ^ ((r >> 2) & 3));
            bf[jj] = L8[256 + cell];
        }
        __builtin_amdgcn_s_setprio(1);
        #pragma unroll
        for (int i = 0; i < 2; ++i)
            #pragma unroll
            for (int jj = 0; jj < 2; ++jj)
                acc[i][jj] = MFMA16(af[i], bf[jj], acc[i][jj]);
        __builtin_amdgcn_s_setprio(0);
        __syncthreads();
    }
#undef G1_STAGE

    if (OMODE != 2) {
        #pragma unroll
        for (int i = 0; i < 2; ++i)
            #pragma unroll
            for (int jj = 0; jj < 2; ++jj) {
                int col = bn0 + wc * 32 + jj * 16 + lr;
                #pragma unroll
                for (int v = 0; v < 4; ++v) {
                    int r = R0 + wr * 32 + i * 16 + lc * 4 + v;
                    float val = acc[i][jj][v];
                    if (BIAS == 2) val += adjrs[r] * bc1p[col] + biasv[col];
                    if (RELU) val = fmaxf(val, 0.f);
                    size_t addr = (OMODE == 1)
                        ? ((size_t)(r >> 9) * 65536 + (size_t)col * 512 + (r & 511))
                        : ((size_t)r * 128 + col);
                    CH[addr] = (f16)val;
                }
            }
    } else {
        // fused maxpool + mention partial sums (adds biasv=b2 first)
        const int b = bidx, rb = (R0 >> 6) & 7, cb = bn0 >> 6;
        int s1 = ments[b * 4 + 0], e1 = ments[b * 4 + 1];
        int s2 = ments[b * 4 + 2], e2 = ments[b * 4 + 3];
        #pragma unroll
        for (int jj = 0; jj < 2; ++jj) {
            int col = bn0 + wc * 32 + jj * 16 + lr;
            float vmax = -INFINITY, v1 = 0.f, v2 = 0.f;
            #pragma unroll
            for (int i = 0; i < 2; ++i)
                #pragma unroll
                for (int v = 0; v < 4; ++v) {
                    int gn = (R0 & 511) + wr * 32 + i * 16 + lc * 4 + v;
                    float val = acc[i][jj][v] + biasv[col];
                    vmax = fmaxf(vmax, val);
                    if (gn >= s1 && gn <= e1) v1 += val;
                    if (gn >= s2 && gn <= e2) v2 += val;
                }
            // reduce across lc (lanes lr, lr+16, lr+32, lr+48)
            #pragma unroll
            for (int off = 16; off <= 32; off <<= 1) {
                vmax = fmaxf(vmax, __shfl_xor(vmax, off, 64));
                v1 += __shfl_xor(v1, off, 64);
                v2 += __shfl_xor(v2, off, 64);
            }
            if (lc == 0) {
                int c = wc * 32 + jj * 16 + lr;
                sred[wr][0][c] = vmax;
                sred[wr][1][c] = v1;
                sred[wr][2][c] = v2;
            }
        }
        __syncthreads();
        if (t < 192) {
            int m = t >> 6, c = t & 63;
            float a0 = sred[0][m][c], a1v = sred[1][m][c];
            float comb = (m == 0) ? fmaxf(a0, a1v) : (a0 + a1v);
            part[((((size_t)b * 8 + rb) * 2 + cb) * 3 + m) * 64 + c] = comb;
        }
    }
}

// ---------------- K5b: combine partials + final linear ----------------
__global__ void k_final2(const float* __restrict__ part, const int* __restrict__ mentions,
                         const float* __restrict__ lw, const float* __restrict__ lb,
                         float* __restrict__ out)
{
    int b = blockIdx.x;
    int t = threadIdx.x;   // 128
    __shared__ float vec[128];
    int s1 = mentions[b * 4 + 0], e1 = mentions[b * 4 + 1];
    int s2 = mentions[b * 4 + 2], e2 = mentions[b * 4 + 3];
    int cb = t >> 6, c = t & 63;
    float pm = -INFINITY, s1s = 0.f, s2s = 0.f;
    #pragma unroll
    for (int rb = 0; rb < 8; ++rb) {
        size_t base = ((((size_t)b * 8 + rb) * 2 + cb) * 3) * 64 + c;
        pm = fmaxf(pm, part[base]);
        s1s += part[base + 64];
        s2s += part[base + 128];
    }
    vec[t] = pm + s1s / (float)(e1 - s1 + 1) + s2s / (float)(e2 - s2 + 1);
    __syncthreads();
    if (t < cNREL) {
        float s = lb[t];
        for (int dd = 0; dd < cOUT; ++dd) s += vec[dd] * lw[dd * cNREL + t];
        out[b * cNREL + t] = s;
    }
}

extern "C" void kernel_launch(void* const* d_in, const int* in_sizes, int n_in,
                              void* d_out, int out_size, void* d_ws, size_t ws_size,
                              hipStream_t stream)
{
    const float* context = (const float*)d_in[0];
    const int*   lens    = (const int*)d_in[1];
    const int*   ments   = (const int*)d_in[2];
    const float* w_enc   = (const float*)d_in[3];
    const float* b_enc   = (const float*)d_in[4];
    const float* glw     = (const float*)d_in[5];
    const float* w1      = (const float*)d_in[6];
    const float* b1      = (const float*)d_in[7];
    const float* w2      = (const float*)d_in[8];
    const float* b2      = (const float*)d_in[9];
    const float* lw      = (const float*)d_in[10];
    const float* lb      = (const float*)d_in[11];
    float* out = (float*)d_out;

    // ---- workspace layout (all disjoint) ----
    f16* XH   = (f16*)d_ws;                      // ARRSZ
    f16* XL   = XH + ARRSZ;                      // ARRSZ
    f16* adjH = XL + ARRSZ;                      // NADJ
    f16* E1t  = adjH + NADJ;                     // NE1
    f16* hH   = E1t + NE1;                       // NE1
    f16* H2t  = hH + NE1;                        // NE1
    f16* RAh  = H2t + NE1;                       // NADJ
    float* G0 = (float*)(RAh + NADJ);            // NADJ f32
    float* invn  = G0 + NADJ;                    // 4*NBN
    float* maskA = invn + 4 * NBN;
    float* rinv  = maskA + NBN;
    float* adjrs = rinv + NBN;
    float* part  = adjrs + NBN;                  // 48*8*2*3*64 = 147456
    float* bc1p  = part + 147456;                // 128
    f16* wc1H = (f16*)(bc1p + 128);              // 128*KP
    f16* w2tH = wc1H + (size_t)128 * KP;         // 128*128
    int* kidx = (int*)(w2tH + 128 * 128);        // NBN*10

    k_prep2<<<NBN / 4, 256, 0, stream>>>(context, lens, glw, maskA, invn, XH, XL);
    k_prepw<<<KP + 1, 128, 0, stream>>>(w_enc, w1, b_enc, w2, wc1H, bc1p, w2tH);
    k_sim_mfma<<<dim3(8, 8, cB), 256, 0, stream>>>(XH, XL, glw, maskA, invn, G0, RAh);
    k_topk<<<NBN / 4, 256, 0, stream>>>(G0, maskA, kidx, rinv);
    k_adj2<<<NBN, 256, 0, stream>>>(RAh, rinv, kidx, adjH, adjrs);

    // E1t = (X @ wc1)^T   [b][128][512]
    k_gemm1<0, false, 1><<<dim3(NBN / 64, 2), 256, 0, stream>>>(
        XH, wc1H, 0, KP, nullptr, nullptr, nullptr, nullptr, E1t, nullptr);
    // h = relu(adj @ E1 + adjrs*bc1p + b1)   [24576][128]
    k_gemm1<2, true, 0><<<dim3(NBN / 64, 2), 256, 0, stream>>>(
        adjH, E1t, 65536, cN, b1, bc1p, adjrs, nullptr, hH, nullptr);
    // H2t = (h @ w2)^T   [b][128][512]
    k_gemm1<0, false, 1><<<dim3(NBN / 64, 2), 256, 0, stream>>>(
        hH, w2tH, 0, cHID, nullptr, nullptr, nullptr, nullptr, H2t, nullptr);
    // nv = adj @ H2 + b2, fused maxpool/mention partials
    k_gemm1<1, false, 2><<<dim3(NBN / 64, 2), 256, 0, stream>>>(
        adjH, H2t, 65536, cN, b2, nullptr, nullptr, ments, nullptr, part);

    k_final2<<<cB, 128, 0, stream>>>(part, ments, lw, lb, out);
}

// Round 6
// 268.707 us; speedup vs baseline: 4.9028x; 1.1028x over previous
//
#include <hip/hip_runtime.h>
#include <math.h>

// Problem constants
constexpr int cB = 48, cN = 512, cIN = 400;
constexpr int cENC = 256, cHID = 128, cOUT = 128, cNREL = 53;
constexpr int cKNN = 10;
constexpr float cVSN = 1e-12f;
constexpr float cEPS = 0.3f;

constexpr int KP = 416;                        // cIN padded to multiple of 32
constexpr size_t ARRSZ = (size_t)cB * cN * KP; // elems per f16 array
constexpr int NBN = cB * cN;                   // 24576 rows
constexpr size_t NADJ = (size_t)cB * cN * cN;  // 12,582,912
constexpr size_t NE1 = (size_t)NBN * 128;      // 3,145,728

typedef _Float16 f16;
typedef _Float16 f16x8 __attribute__((ext_vector_type(8)));
typedef float f32x4 __attribute__((ext_vector_type(4)));

__device__ inline unsigned long long shfl_xor_u64(unsigned long long v, int off) {
    int lo = __shfl_xor((int)(unsigned)(v & 0xffffffffull), off, 64);
    int hi = __shfl_xor((int)(unsigned)(v >> 32), off, 64);
    return ((unsigned long long)(unsigned)hi << 32) | (unsigned)lo;
}

__device__ inline void gload16(const void* g, void* l) {
    __builtin_amdgcn_global_load_lds(
        (const __attribute__((address_space(1))) unsigned int*)g,
        (__attribute__((address_space(3))) unsigned int*)l, 16, 0, 0);
}

#define MFMA16(a, b, c) __builtin_amdgcn_mfma_f32_16x16x32_f16((a), (b), (c), 0, 0, 0)

// ---------------- K0: merged prep ----------------
// blocks [0, NBN/4): mask + inv-norms + XH f16 array (vectorized)
// blocks [NBN/4, NBN/4+KP+1): weight prep (wc1 = w_enc@w1 as f16^T, w2^T, bc1p)
__global__ void k_prep(const float* __restrict__ X, const int* __restrict__ lens,
                       const float* __restrict__ glw,
                       const float* __restrict__ w_enc, const float* __restrict__ w1,
                       const float* __restrict__ b_enc, const float* __restrict__ w2,
                       float* __restrict__ mask, float* __restrict__ invn,
                       f16* __restrict__ XH,
                       f16* __restrict__ wc1H, float* __restrict__ bc1p,
                       f16* __restrict__ w2tH)
{
    int bid = blockIdx.x;
    int t = threadIdx.x;
    if (bid >= NBN / 4) {
        // ---- weight prep part ----
        int d = bid - NBN / 4;   // 0..KP
        int o = t;
        if (o < 128) {
            if (d < KP) {
                float acc = 0.f;
                if (d < cIN)
                    for (int e = 0; e < cENC; ++e)
                        acc += w_enc[(size_t)d * cENC + e] * w1[(size_t)e * cHID + o];
                wc1H[(size_t)o * KP + d] = (f16)acc;
                if (d < cHID)
                    w2tH[(size_t)o * cHID + d] = (f16)w2[(size_t)d * cOUT + o];
            } else {
                float acc = 0.f;
                for (int e = 0; e < cENC; ++e) acc += b_enc[e] * w1[(size_t)e * cHID + o];
                bc1p[o] = acc;
            }
        }
        return;
    }
    // ---- row prep part: 4 rows per block, 1 wave per row ----
    int row = bid * 4 + (t >> 6);
    int lane = t & 63;
    int b = row >> 9, n = row & (cN - 1);
    const float* x = X + (size_t)row * cIN;
    bool act = lane < 50;
    int k = lane * 8;
    float4 z4 = make_float4(0.f, 0.f, 0.f, 0.f);
    float4 xa = act ? *(const float4*)&x[k]     : z4;
    float4 xb = act ? *(const float4*)&x[k + 4] : z4;
    float xv[8] = {xa.x, xa.y, xa.z, xa.w, xb.x, xb.y, xb.z, xb.w};
    float s[4] = {0.f, 0.f, 0.f, 0.f};
    #pragma unroll
    for (int p = 0; p < 4; ++p) {
        float4 ga = act ? *(const float4*)&glw[p * cIN + k]     : z4;
        float4 gb = act ? *(const float4*)&glw[p * cIN + k + 4] : z4;
        float gv[8] = {ga.x, ga.y, ga.z, ga.w, gb.x, gb.y, gb.z, gb.w};
        #pragma unroll
        for (int e = 0; e < 8; ++e) {
            float t2 = xv[e] * gv[e];
            s[p] += t2 * t2;
        }
    }
    f16x8 vh;
    #pragma unroll
    for (int e = 0; e < 8; ++e) vh[e] = (f16)xv[e];
    if (lane < 52) *(f16x8*)(XH + (size_t)row * KP + k) = vh;   // lanes 50/51 write pad zeros
    #pragma unroll
    for (int off = 32; off; off >>= 1) {
        s[0] += __shfl_xor(s[0], off, 64);
        s[1] += __shfl_xor(s[1], off, 64);
        s[2] += __shfl_xor(s[2], off, 64);
        s[3] += __shfl_xor(s[3], off, 64);
    }
    if (lane == 0) {
        mask[row] = (n < lens[b]) ? 1.0f : 0.0f;
        invn[0 * NBN + row] = 1.0f / fmaxf(sqrtf(s[0]), cVSN);
        invn[1 * NBN + row] = 1.0f / fmaxf(sqrtf(s[1]), cVSN);
        invn[2 * NBN + row] = 1.0f / fmaxf(sqrtf(s[2]), cVSN);
        invn[3 * NBN + row] = 1.0f / fmaxf(sqrtf(s[3]), cVSN);
    }
}

// ---------------- K1: MFMA similarity, 5 passes, 2-tile staging, double-buffered ----
__global__ __launch_bounds__(256, 3) void k_sim_mfma(
    const f16* __restrict__ XH,
    const float* __restrict__ glw,
    const float* __restrict__ maskA, const float* __restrict__ invn,
    float* __restrict__ G0, f16* __restrict__ RAh)
{
    // bijective XCD swizzle: all 64 blocks of a batch on one XCD
    int L = blockIdx.x + (blockIdx.y << 3) + (blockIdx.z << 6);
    int xcd = L & 7, j0 = L >> 3;
    int work = xcd * 384 + j0;
    const int b = work >> 6;
    int rem = work & 63;
    const int n0 = (rem >> 3) * 64, m0 = (rem & 7) * 64;

    const int t = threadIdx.x;
    const int w = t >> 6, lane = t & 63;
    const int wr = w >> 1, wc = w & 1;
    const int lr = lane & 15, lc = lane >> 4;

    __shared__ f16 lds[2][4096];   // 2 bufs x 2 tiles x [64 rows][4 slots][8 f16]
    __shared__ f16 w2l[4][KP];

    for (int i = t; i < 4 * KP; i += 256) {
        int p = i / KP, d = i - p * KP;
        float g = (d < cIN) ? glw[p * cIN + d] : 0.f;
        w2l[p][d] = (f16)(g * g);
    }

    f32x4 accG[2][2], accP[4][2][2];
    #pragma unroll
    for (int i = 0; i < 2; ++i)
        #pragma unroll
        for (int jj = 0; jj < 2; ++jj) {
            accG[i][jj] = (f32x4)0.f;
            #pragma unroll
            for (int p = 0; p < 4; ++p) accP[p][i][jj] = (f32x4)0.f;
        }

    const size_t rowBaseB = (size_t)b * cN;

#define SIM_STAGE(buf, pan) do { \
    const int kk0_ = (pan) * 32; \
    _Pragma("unroll") \
    for (int q = 0; q < 2; ++q) { \
        int c_ = w + q * 4;               /* chunk 0..7, wave-uniform */ \
        int tt_ = c_ >> 2;                /* tile: 0 = n0-rows, 1 = m0-rows */ \
        int rq_ = c_ & 3; \
        int row_ = rq_ * 16 + (lane >> 2); \
        int kcg_ = (lane & 3) ^ (row_ & 3) ^ ((row_ >> 2) & 3); \
        int rb_ = tt_ ? m0 : n0; \
        const f16* g_ = XH + (rowBaseB + rb_ + row_) * (size_t)KP + kk0_ + kcg_ * 8; \
        gload16(g_, (void*)&lds[buf][tt_ * 2048 + rq_ * 512]); \
    } \
} while (0)

    SIM_STAGE(0, 0);
    __syncthreads();

    for (int pan = 0; pan < KP / 32; ++pan) {
        int cur = pan & 1;
        if (pan + 1 < KP / 32) SIM_STAGE(cur ^ 1, pan + 1);
        const f16x8* L8 = (const f16x8*)lds[cur];
        const int kk0 = pan * 32;
        f16x8 aH[2], bH[2], wp[4];
        #pragma unroll
        for (int i = 0; i < 2; ++i) {
            int r = wr * 32 + i * 16 + lr;
            int cell = r * 4 + (lc ^ (r & 3) ^ ((r >> 2) & 3));
            aH[i] = L8[cell];
        }
        #pragma unroll
        for (int jj = 0; jj < 2; ++jj) {
            int r = wc * 32 + jj * 16 + lr;
            int cell = r * 4 + (lc ^ (r & 3) ^ ((r >> 2) & 3));
            bH[jj] = L8[256 + cell];
        }
        #pragma unroll
        for (int p = 0; p < 4; ++p) wp[p] = *(const f16x8*)&w2l[p][kk0 + lc * 8];

        __builtin_amdgcn_s_setprio(1);
        #pragma unroll
        for (int i = 0; i < 2; ++i)
            #pragma unroll
            for (int jj = 0; jj < 2; ++jj)
                accG[i][jj] = MFMA16(aH[i], bH[jj], accG[i][jj]);
        #pragma unroll
        for (int p = 0; p < 4; ++p)
            #pragma unroll
            for (int i = 0; i < 2; ++i) {
                f16x8 ap = aH[i] * wp[p];
                #pragma unroll
                for (int jj = 0; jj < 2; ++jj)
                    accP[p][i][jj] = MFMA16(ap, bH[jj], accP[p][i][jj]);
            }
        __builtin_amdgcn_s_setprio(0);
        __syncthreads();
    }
#undef SIM_STAGE

    // epilogue: mask, cosine-normalize, sparsify; G0 NT (streamed), RA normal (L2/L3)
    #pragma unroll
    for (int i = 0; i < 2; ++i) {
        #pragma unroll
        for (int jj = 0; jj < 2; ++jj) {
            int m = m0 + wc * 32 + jj * 16 + lr;
            size_t rowm = rowBaseB + m;
            float mskm = maskA[rowm];
            float im0 = invn[0 * NBN + rowm], im1 = invn[1 * NBN + rowm];
            float im2 = invn[2 * NBN + rowm], im3 = invn[3 * NBN + rowm];
            #pragma unroll
            for (int v = 0; v < 4; ++v) {
                int n = n0 + wr * 32 + i * 16 + lc * 4 + v;
                size_t rown = rowBaseB + n;
                float mk = maskA[rown] * mskm;
                float g = accG[i][jj][v] * mk;
                float s = 0.25f * (accP[0][i][jj][v] * invn[0 * NBN + rown] * im0
                                 + accP[1][i][jj][v] * invn[1 * NBN + rown] * im1
                                 + accP[2][i][jj][v] * invn[2 * NBN + rown] * im2
                                 + accP[3][i][jj][v] * invn[3 * NBN + rown] * im3) * mk;
                float rv = (s > cEPS) ? s : 0.f;
                __builtin_nontemporal_store(g, &G0[rown * cN + m]);
                RAh[rown * cN + m] = (f16)rv;
            }
        }
    }
}

// ---------------- K2: per-row top-10 (value desc, index asc) ----------------
__global__ void k_topk(const float* __restrict__ G0, const float* __restrict__ mask,
                       int* __restrict__ kidx, float* __restrict__ rinv)
{
    int row = blockIdx.x * 4 + (threadIdx.x >> 6);
    int lane = threadIdx.x & 63;
    int b = row >> 9, n = row & (cN - 1);
    const float* g = G0 + (long long)row * cN;
    unsigned long long key[8];
    #pragma unroll
    for (int k = 0; k < 8; ++k) {
        int col = lane + 64 * k;
        float v = __builtin_nontemporal_load(&g[col]);
        unsigned u = __float_as_uint(v);
        u ^= (unsigned)(((int)u >> 31)) | 0x80000000u;
        key[k] = ((unsigned long long)u << 32) | (unsigned)(cN - 1 - col);
    }
    float cnt = 0.f;
    long long mbase = (long long)b * cN;
    for (int r = 0; r < cKNN; ++r) {
        unsigned long long best = 0ull;
        #pragma unroll
        for (int k = 0; k < 8; ++k) best = (key[k] > best) ? key[k] : best;
        #pragma unroll
        for (int off = 32; off; off >>= 1) {
            unsigned long long o = shfl_xor_u64(best, off);
            if (o > best) best = o;
        }
        int col = (cN - 1) - (int)(best & 0xffffffffull);
        #pragma unroll
        for (int k = 0; k < 8; ++k) if (key[k] == best) key[k] = 0ull;
        if (lane == 0) {
            kidx[row * cKNN + r] = col;
            cnt += mask[mbase + col];
        }
    }
    if (lane == 0) {
        float mk = mask[mbase + n];
        rinv[row] = (mk > 0.f) ? rsqrtf(fmaxf(cnt, cVSN)) : 0.f;
    }
}

// ---------------- K3: adjacency assembly (fused rowsum, single f16 out, adjrs) -----
__global__ void k_adj2(const f16* __restrict__ RAh, const float* __restrict__ rinv,
                       const int* __restrict__ kidx,
                       f16* __restrict__ adjH, float* __restrict__ adjrs)
{
    int row = blockIdx.x;
    int t = threadIdx.x;  // 256
    int w = t >> 6, lane = t & 63;
    __shared__ int sidx[cKNN];
    __shared__ float srv[cKNN];
    __shared__ float red[4];
    long long bbase = (long long)(row & ~(cN - 1));
    if (t < cKNN) {
        int c = kidx[row * cKNN + t];
        sidx[t] = c;
        srv[t] = rinv[bbase + c];
    }
    long long base = (long long)row * cN;
    float ra0 = (float)RAh[base + t];
    float ra1 = (float)RAh[base + t + 256];
    float s = ra0 + ra1;
    #pragma unroll
    for (int off = 32; off; off >>= 1) s += __shfl_xor(s, off, 64);
    if (lane == 0) red[w] = s;
    __syncthreads();
    float rsum = red[0] + red[1] + red[2] + red[3];
    float inv_rs = 1.0f / fmaxf(rsum, cVSN);
    float rn = rinv[row];
    float osum = 0.f;
    #pragma unroll
    for (int mi = 0; mi < 2; ++mi) {
        int m = t + mi * 256;
        float ra = mi ? ra1 : ra0;
        float v = 0.2f * ra * inv_rs;
        #pragma unroll
        for (int k = 0; k < cKNN; ++k)
            if (m == sidx[k]) v += 0.8f * rn * srv[k];
        adjH[base + m] = (f16)v;
        osum += v;
    }
    #pragma unroll
    for (int off = 32; off; off >>= 1) osum += __shfl_xor(osum, off, 64);
    __syncthreads();
    if (lane == 0) red[w] = osum;
    __syncthreads();
    if (t == 0) adjrs[row] = red[0] + red[1] + red[2] + red[3];
}

// ---------------- Single-pass f16 MFMA GEMM, BM=64 BN=64 BK=32, double-buffered ----
// BIAS: 0 none, 1 +biasv[col] (OMODE2), 2 +adjrs[row]*bc1p[col]+biasv[col]
// OMODE: 0 f16 flat [r][128], 1 f16 transposed [b][col][512], 2 fused pool partials
template<int BIAS, bool RELU, int OMODE>
__global__ __launch_bounds__(256, 4) void k_gemm1(
    const f16* __restrict__ A, const f16* __restrict__ Bp,
    long long bStrideB, int K,
    const float* __restrict__ biasv, const float* __restrict__ bc1p,
    const float* __restrict__ adjrs, const int* __restrict__ ments,
    f16* __restrict__ CH, float* __restrict__ part)
{
    // bijective XCD swizzle over 768 blocks; (R0, both bn) consecutive per XCD
    int L = blockIdx.x + blockIdx.y * gridDim.x;
    int work = (L & 7) * 96 + (L >> 3);
    const int R0 = (work >> 1) * 64;
    const int bn0 = (work & 1) * 64;
    const int bidx = R0 >> 9;
    const int t = threadIdx.x, w = t >> 6, lane = t & 63;
    const int wr = w >> 1, wc = w & 1, lr = lane & 15, lc = lane >> 4;
    __shared__ f16 lds[2][4096];   // 2 x 8KB: A cells 0..255, B cells 256..511
    __shared__ float sred[2][3][64];
    const f16* Bb = Bp + (size_t)bidx * bStrideB + (size_t)bn0 * K;

    f32x4 acc[2][2];
    #pragma unroll
    for (int i = 0; i < 2; ++i)
        #pragma unroll
        for (int jj = 0; jj < 2; ++jj) acc[i][jj] = (f32x4)0.f;

#define G1_STAGE(buf, p_) do { \
    const int k0_ = (p_) * 32; \
    _Pragma("unroll") \
    for (int q = 0; q < 2; ++q) { \
        int c_ = w + q * 4; \
        int rq_ = c_ & 3; \
        int row_ = rq_ * 16 + (lane >> 2); \
        int kc_ = (lane & 3) ^ (row_ & 3) ^ ((row_ >> 2) & 3); \
        const f16* src_ = (c_ < 4) ? (A + (size_t)(R0 + row_) * K + k0_ + kc_ * 8) \
                                   : (Bb + (size_t)row_ * K + k0_ + kc_ * 8); \
        gload16(src_, (void*)&lds[buf][(c_ >> 2) * 2048 + rq_ * 512]); \
    } \
} while (0)

    const int npan = K >> 5;
    G1_STAGE(0, 0);
    __syncthreads();
    for (int p = 0; p < npan; ++p) {
        int cur = p & 1;
        if (p + 1 < npan) G1_STAGE(cur ^ 1, p + 1);
        const f16x8* L8 = (const f16x8*)lds[cur];
        f16x8 af[2], bf[2];
        #pragma unroll
        for (int i = 0; i < 2; ++i) {
            int r = wr * 32 + i * 16 + lr;
            int cell = r * 4 + (lc ^ (r & 3) ^ ((r >> 2) & 3));
            af[i] = L8[cell];
        }
        #pragma unroll
        for (int jj = 0; jj < 2; ++jj) {
            int r = wc * 32 + jj * 16 + lr;
            int cell = r * 4 + (lc ^ (r & 3) ^ ((r >> 2) & 3));
            bf[jj] = L8[256 + cell];
        }
        __builtin_amdgcn_s_setprio(1);
        #pragma unroll
        for (int i = 0; i < 2; ++i)
            #pragma unroll
            for (int jj = 0; jj < 2; ++jj)
                acc[i][jj] = MFMA16(af[i], bf[jj], acc[i][jj]);
        __builtin_amdgcn_s_setprio(0);
        __syncthreads();
    }
#undef G1_STAGE

    if (OMODE != 2) {
        #pragma unroll
        for (int i = 0; i < 2; ++i)
            #pragma unroll
            for (int jj = 0; jj < 2; ++jj) {
                int col = bn0 + wc * 32 + jj * 16 + lr;
                #pragma unroll
                for (int v = 0; v < 4; ++v) {
                    int r = R0 + wr * 32 + i * 16 + lc * 4 + v;
                    float val = acc[i][jj][v];
                    if (BIAS == 2) val += adjrs[r] * bc1p[col] + biasv[col];
                    if (RELU) val = fmaxf(val, 0.f);
                    size_t addr = (OMODE == 1)
                        ? ((size_t)(r >> 9) * 65536 + (size_t)col * 512 + (r & 511))
                        : ((size_t)r * 128 + col);
                    CH[addr] = (f16)val;
                }
            }
    } else {
        // fused maxpool + mention partial sums (adds biasv=b2 first)
        const int b = bidx, rb = (R0 >> 6) & 7, cb = bn0 >> 6;
        int s1 = ments[b * 4 + 0], e1 = ments[b * 4 + 1];
        int s2 = ments[b * 4 + 2], e2 = ments[b * 4 + 3];
        #pragma unroll
        for (int jj = 0; jj < 2; ++jj) {
            int col = bn0 + wc * 32 + jj * 16 + lr;
            float vmax = -INFINITY, v1 = 0.f, v2 = 0.f;
            #pragma unroll
            for (int i = 0; i < 2; ++i)
                #pragma unroll
                for (int v = 0; v < 4; ++v) {
                    int gn = (R0 & 511) + wr * 32 + i * 16 + lc * 4 + v;
                    float val = acc[i][jj][v] + biasv[col];
                    vmax = fmaxf(vmax, val);
                    if (gn >= s1 && gn <= e1) v1 += val;
                    if (gn >= s2 && gn <= e2) v2 += val;
                }
            #pragma unroll
            for (int off = 16; off <= 32; off <<= 1) {
                vmax = fmaxf(vmax, __shfl_xor(vmax, off, 64));
                v1 += __shfl_xor(v1, off, 64);
                v2 += __shfl_xor(v2, off, 64);
            }
            if (lc == 0) {
                int c = wc * 32 + jj * 16 + lr;
                sred[wr][0][c] = vmax;
                sred[wr][1][c] = v1;
                sred[wr][2][c] = v2;
            }
        }
        __syncthreads();
        if (t < 192) {
            int m = t >> 6, c = t & 63;
            float a0 = sred[0][m][c], a1v = sred[1][m][c];
            float comb = (m == 0) ? fmaxf(a0, a1v) : (a0 + a1v);
            part[((((size_t)b * 8 + rb) * 2 + cb) * 3 + m) * 64 + c] = comb;
        }
    }
}

// ---------------- K5b: combine partials + final linear ----------------
__global__ void k_final2(const float* __restrict__ part, const int* __restrict__ mentions,
                         const float* __restrict__ lw, const float* __restrict__ lb,
                         float* __restrict__ out)
{
    int b = blockIdx.x;
    int t = threadIdx.x;   // 128
    __shared__ float vec[128];
    int s1 = mentions[b * 4 + 0], e1 = mentions[b * 4 + 1];
    int s2 = mentions[b * 4 + 2], e2 = mentions[b * 4 + 3];
    int cb = t >> 6, c = t & 63;
    float pm = -INFINITY, s1s = 0.f, s2s = 0.f;
    #pragma unroll
    for (int rb = 0; rb < 8; ++rb) {
        size_t base = ((((size_t)b * 8 + rb) * 2 + cb) * 3) * 64 + c;
        pm = fmaxf(pm, part[base]);
        s1s += part[base + 64];
        s2s += part[base + 128];
    }
    vec[t] = pm + s1s / (float)(e1 - s1 + 1) + s2s / (float)(e2 - s2 + 1);
    __syncthreads();
    if (t < cNREL) {
        float s = lb[t];
        for (int dd = 0; dd < cOUT; ++dd) s += vec[dd] * lw[dd * cNREL + t];
        out[b * cNREL + t] = s;
    }
}

extern "C" void kernel_launch(void* const* d_in, const int* in_sizes, int n_in,
                              void* d_out, int out_size, void* d_ws, size_t ws_size,
                              hipStream_t stream)
{
    const float* context = (const float*)d_in[0];
    const int*   lens    = (const int*)d_in[1];
    const int*   ments   = (const int*)d_in[2];
    const float* w_enc   = (const float*)d_in[3];
    const float* b_enc   = (const float*)d_in[4];
    const float* glw     = (const float*)d_in[5];
    const float* w1      = (const float*)d_in[6];
    const float* b1      = (const float*)d_in[7];
    const float* w2      = (const float*)d_in[8];
    const float* b2      = (const float*)d_in[9];
    const float* lw      = (const float*)d_in[10];
    const float* lb      = (const float*)d_in[11];
    float* out = (float*)d_out;

    // ---- workspace layout (all disjoint) ----
    f16* XH   = (f16*)d_ws;                      // ARRSZ
    f16* adjH = XH + ARRSZ;                      // NADJ
    f16* E1t  = adjH + NADJ;                     // NE1
    f16* hH   = E1t + NE1;                       // NE1
    f16* H2t  = hH + NE1;                        // NE1
    f16* RAh  = H2t + NE1;                       // NADJ
    float* G0 = (float*)(RAh + NADJ);            // NADJ f32
    float* invn  = G0 + NADJ;                    // 4*NBN
    float* maskA = invn + 4 * NBN;
    float* rinv  = maskA + NBN;
    float* adjrs = rinv + NBN;
    float* part  = adjrs + NBN;                  // 48*8*2*3*64 = 147456
    float* bc1p  = part + 147456;                // 128
    f16* wc1H = (f16*)(bc1p + 128);              // 128*KP
    f16* w2tH = wc1H + (size_t)128 * KP;         // 128*128
    int* kidx = (int*)(w2tH + 128 * 128);        // NBN*10

    k_prep<<<NBN / 4 + KP + 1, 256, 0, stream>>>(
        context, lens, glw, w_enc, w1, b_enc, w2, maskA, invn, XH, wc1H, bc1p, w2tH);
    k_sim_mfma<<<dim3(8, 8, cB), 256, 0, stream>>>(XH, glw, maskA, invn, G0, RAh);
    k_topk<<<NBN / 4, 256, 0, stream>>>(G0, maskA, kidx, rinv);
    k_adj2<<<NBN, 256, 0, stream>>>(RAh, rinv, kidx, adjH, adjrs);

    // E1t = (X @ wc1)^T   [b][128][512]
    k_gemm1<0, false, 1><<<dim3(NBN / 64, 2), 256, 0, stream>>>(
        XH, wc1H, 0, KP, nullptr, nullptr, nullptr, nullptr, E1t, nullptr);
    // h = relu(adj @ E1 + adjrs*bc1p + b1)   [24576][128]
    k_gemm1<2, true, 0><<<dim3(NBN / 64, 2), 256, 0, stream>>>(
        adjH, E1t, 65536, cN, b1, bc1p, adjrs, nullptr, hH, nullptr);
    // H2t = (h @ w2)^T   [b][128][512]
    k_gemm1<0, false, 1><<<dim3(NBN / 64, 2), 256, 0, stream>>>(
        hH, w2tH, 0, cHID, nullptr, nullptr, nullptr, nullptr, H2t, nullptr);
    // nv = adj @ H2 + b2, fused maxpool/mention partials
    k_gemm1<1, false, 2><<<dim3(NBN / 64, 2), 256, 0, stream>>>(
        adjH, H2t, 65536, cN, b2, nullptr, nullptr, ments, nullptr, part);

    k_final2<<<cB, 128, 0, stream>>>(part, ments, lw, lb, out);
}